// Round 2
// baseline (4397.227 us; speedup 1.0000x reference)
//
#include <hip/hip_runtime.h>
#include <math.h>

#define NAT 100000
#define MNB 12
#define FEA 64
#define NBRF 41
#define C2 128
#define HIDD 768
#define NCONV 3
#define BB 32
#define LL 512
#define EPSV 1e-5f
#define CONV_BLKS (NAT / 8)   // 12500 blocks, 8 samples each

typedef short bf16x8 __attribute__((ext_vector_type(8)));
typedef float f32x4 __attribute__((ext_vector_type(4)));

__device__ __forceinline__ float softplus_f(float x) {
    if (x > 20.f) return x;
    return log1pf(__expf(x));
}
__device__ __forceinline__ float sigmoid_f(float x) {
    return 1.f / (1.f + __expf(-x));
}
__device__ __forceinline__ unsigned short f2bf(float x) {
    union { float f; unsigned u; } v; v.f = x;
    unsigned r = v.u + 0x7fff + ((v.u >> 16) & 1);
    return (unsigned short)(r >> 16);
}
__device__ __forceinline__ float bf2f(unsigned short u) {
    union { unsigned u; float f; } v; v.u = ((unsigned)u) << 16; return v.f;
}

// ---------------------------------------------------------------- embed
__global__ __launch_bounds__(256) void k_embed(const int* __restrict__ anum,
                                               const float* __restrict__ emb,
                                               float* __restrict__ af) {
    int idx = blockIdx.x * 256 + threadIdx.x;
    if (idx >= NAT * FEA) return;
    int n = idx >> 6, c = idx & 63;
    af[idx] = emb[anum[n] * FEA + c];
}

// ---------------- S = af@W[0:64]+b (bf16), T = af@W[64:128] (bf16)
__global__ __launch_bounds__(256) void k_st(const float* __restrict__ af,
                                            const float* __restrict__ Wb,
                                            const float* __restrict__ bb,
                                            unsigned short* __restrict__ S16,
                                            unsigned short* __restrict__ T16) {
    __shared__ float Ws[64][128];
    __shared__ float As[16][65];
    int tid = threadIdx.x;
    int a0 = blockIdx.x * 16;
    for (int t = tid; t < 16 * 64; t += 256) {
        int a = t >> 6, k = t & 63;
        As[a][k] = af[(size_t)(a0 + a) * FEA + k];
    }
    int a = tid >> 4, c0 = tid & 15;
    int n = a0 + a;
    for (int half = 0; half < 2; ++half) {
        __syncthreads();
        for (int t = tid; t < 64 * 128; t += 256) {
            int k = t >> 7, c = t & 127;
            Ws[k][c] = Wb[(size_t)(half * 64 + k) * C2 + c];
        }
        __syncthreads();
        float acc[8];
        #pragma unroll
        for (int j = 0; j < 8; ++j) acc[j] = 0.f;
        for (int k = 0; k < 64; ++k) {
            float av = As[a][k];
            #pragma unroll
            for (int j = 0; j < 8; ++j)
                acc[j] = fmaf(av, Ws[k][c0 + j * 16], acc[j]);
        }
        if (half == 0) {
            #pragma unroll
            for (int j = 0; j < 8; ++j) {
                int c = c0 + j * 16;
                S16[(size_t)n * C2 + c] = f2bf(acc[j] + bb[c]);
            }
        } else {
            #pragma unroll
            for (int j = 0; j < 8; ++j)
                T16[(size_t)n * C2 + c0 + j * 16] = f2bf(acc[j]);
        }
    }
}

// ---------------- fused conv pass: MFMA nbr-GEMM + gather + reduce
// MODE 0: BN1 stats (per-channel sum/sumsq of gated, 128 ch)
// MODE 1: BN1 apply + gate + m-sum -> summed; BN2 stats (64 ch)
template<int MODE>
__global__ __launch_bounds__(256) void k_conv(const unsigned short* __restrict__ S16,
                                              const unsigned short* __restrict__ T16,
                                              const float* __restrict__ nf,
                                              const int* __restrict__ nidx,
                                              const float* __restrict__ Wb,
                                              const float* __restrict__ sc1,
                                              const float* __restrict__ sh1,
                                              float* __restrict__ summed,
                                              float* __restrict__ psum,
                                              float* __restrict__ psq) {
    __shared__ unsigned short WnT[C2 * 64];      // [col][swizzled k], k padded to 64
    __shared__ unsigned short As[8 * 16 * 64];   // [sample][row(16)][swizzled k]
    __shared__ int NIl[96];
    __shared__ float red1[4][C2];
    __shared__ float red2[4][C2];

    int tid = threadIdx.x;
    int blk = blockIdx.x;
    int n0 = blk * 8;

    for (int e = tid; e < C2 * 64; e += 256) WnT[e] = 0;
    __syncthreads();
    for (int e = tid; e < NBRF * C2; e += 256) {
        int k = e >> 7, c = e & 127;
        WnT[c * 64 + 8 * ((k >> 3) ^ (c & 7)) + (k & 7)] =
            f2bf(Wb[(size_t)(128 + k) * C2 + c]);
    }
    const float* src = nf + (size_t)n0 * (MNB * NBRF);
    for (int e = tid; e < 8 * 12 * 64; e += 256) {
        int s = e / 768;
        int rem = e - s * 768;
        int r = rem >> 6, k = rem & 63;
        float v = (k < NBRF) ? src[(s * 12 + r) * NBRF + k] : 0.f;
        As[(s * 16 + r) * 64 + 8 * ((k >> 3) ^ (r & 7)) + (k & 7)] = f2bf(v);
    }
    if (tid < 96) NIl[tid] = nidx[(size_t)n0 * MNB + tid];
    __syncthreads();

    int w = tid >> 6, l = tid & 63;
    int c_loc = l & 15, kg = l >> 4;

    // hoisted B fragments: 8 col-tiles x 2 K-steps
    bf16x8 bfr[16];
    #pragma unroll
    for (int ct = 0; ct < 8; ++ct) {
        int c = ct * 16 + c_loc;
        #pragma unroll
        for (int kk = 0; kk < 2; ++kk) {
            int kb = kk * 4 + kg;
            bfr[ct * 2 + kk] = *(const bf16x8*)&WnT[c * 64 + 8 * (kb ^ (c & 7))];
        }
    }
    float sc1v[8], sh1v[8];
    if (MODE == 1) {
        #pragma unroll
        for (int ct = 0; ct < 8; ++ct) {
            sc1v[ct] = sc1[ct * 16 + c_loc];
            sh1v[ct] = sh1[ct * 16 + c_loc];
        }
    }

    float accA[8], accB[8];
    #pragma unroll
    for (int i = 0; i < 8; ++i) { accA[i] = 0.f; accB[i] = 0.f; }

    for (int sw = 0; sw < 2; ++sw) {
        int s = w + 4 * sw;
        int n = n0 + s;
        bf16x8 afr[2];
        #pragma unroll
        for (int kk = 0; kk < 2; ++kk) {
            int r = c_loc;                 // A row = lane&15
            int kb = kk * 4 + kg;
            afr[kk] = *(const bf16x8*)&As[(s * 16 + r) * 64 + 8 * (kb ^ (r & 7))];
        }
        f32x4 acc[8];
        #pragma unroll
        for (int ct = 0; ct < 8; ++ct) {
            acc[ct] = f32x4{0.f, 0.f, 0.f, 0.f};
            acc[ct] = __builtin_amdgcn_mfma_f32_16x16x32_bf16(afr[0], bfr[ct * 2 + 0], acc[ct], 0, 0, 0);
            acc[ct] = __builtin_amdgcn_mfma_f32_16x16x32_bf16(afr[1], bfr[ct * 2 + 1], acc[ct], 0, 0, 0);
        }
        float Sv[8];
        #pragma unroll
        for (int ct = 0; ct < 8; ++ct)
            Sv[ct] = bf2f(S16[(size_t)n * C2 + ct * 16 + c_loc]);
        int jrow[4];
        #pragma unroll
        for (int r2 = 0; r2 < 4; ++r2) {
            int m = kg * 4 + r2;
            jrow[r2] = NIl[s * 12 + (m < 12 ? m : 0)];
        }
        bool valid = (kg < 3);   // rows 12..15 are pad

        if (MODE == 0) {
            float sm[8], sq[8];
            #pragma unroll
            for (int ct = 0; ct < 8; ++ct) { sm[ct] = 0.f; sq[ct] = 0.f; }
            #pragma unroll
            for (int r2 = 0; r2 < 4; ++r2) {
                if (valid) {
                    #pragma unroll
                    for (int ct = 0; ct < 8; ++ct) {
                        float Tv = bf2f(T16[(size_t)jrow[r2] * C2 + ct * 16 + c_loc]);
                        float g = acc[ct][r2] + Sv[ct] + Tv;
                        sm[ct] += g; sq[ct] += g * g;
                    }
                }
            }
            #pragma unroll
            for (int ct = 0; ct < 8; ++ct) {
                sm[ct] += __shfl_xor(sm[ct], 16); sm[ct] += __shfl_xor(sm[ct], 32);
                sq[ct] += __shfl_xor(sq[ct], 16); sq[ct] += __shfl_xor(sq[ct], 32);
                accA[ct] += sm[ct]; accB[ct] += sq[ct];
            }
        } else {
            float vsum[4] = {0.f, 0.f, 0.f, 0.f};
            #pragma unroll
            for (int r2 = 0; r2 < 4; ++r2) {
                if (valid) {
                    float g[8];
                    #pragma unroll
                    for (int ct = 0; ct < 8; ++ct) {
                        float Tv = bf2f(T16[(size_t)jrow[r2] * C2 + ct * 16 + c_loc]);
                        g[ct] = (acc[ct][r2] + Sv[ct] + Tv) * sc1v[ct] + sh1v[ct];
                    }
                    #pragma unroll
                    for (int ct = 0; ct < 4; ++ct)
                        vsum[ct] += sigmoid_f(g[ct]) * softplus_f(g[ct + 4]);
                }
            }
            #pragma unroll
            for (int ct = 0; ct < 4; ++ct) {
                vsum[ct] += __shfl_xor(vsum[ct], 16);
                vsum[ct] += __shfl_xor(vsum[ct], 32);
                if (l < 16) summed[(size_t)n * FEA + ct * 16 + l] = vsum[ct];
                accA[ct] += vsum[ct]; accB[ct] += vsum[ct] * vsum[ct];
            }
        }
    }

    if (l < 16) {
        int ncts = (MODE == 0) ? 8 : 4;
        for (int ct = 0; ct < ncts; ++ct) {
            red1[w][ct * 16 + l] = accA[ct];
            red2[w][ct * 16 + l] = accB[ct];
        }
    }
    __syncthreads();
    int cch = (MODE == 0) ? C2 : FEA;
    if (tid < cch) {
        float ts = red1[0][tid] + red1[1][tid] + red1[2][tid] + red1[3][tid];
        float tq = red2[0][tid] + red2[1][tid] + red2[2][tid] + red2[3][tid];
        psum[(size_t)tid * CONV_BLKS + blk] = ts;
        psq[(size_t)tid * CONV_BLKS + blk] = tq;
    }
}

// ---------------- BN finalize
__global__ __launch_bounds__(256) void k_bnfin(const float* __restrict__ psum,
                                               const float* __restrict__ psq,
                                               const float* __restrict__ g,
                                               const float* __restrict__ b,
                                               float cnt_inv,
                                               float* __restrict__ scale,
                                               float* __restrict__ shift) {
    int c = blockIdx.x;
    int tid = threadIdx.x;
    __shared__ float r1[256], r2[256];
    float s = 0.f, q = 0.f;
    for (int t = tid; t < CONV_BLKS; t += 256) {
        s += psum[(size_t)c * CONV_BLKS + t];
        q += psq[(size_t)c * CONV_BLKS + t];
    }
    r1[tid] = s; r2[tid] = q;
    __syncthreads();
    for (int st = 128; st > 0; st >>= 1) {
        if (tid < st) { r1[tid] += r1[tid + st]; r2[tid] += r2[tid + st]; }
        __syncthreads();
    }
    if (tid == 0) {
        float mean = r1[0] * cnt_inv;
        float var = r2[0] * cnt_inv - mean * mean;
        float sc = g[c] * rsqrtf(var + EPSV);
        scale[c] = sc;
        shift[c] = b[c] - mean * sc;
    }
}

// ---------------- residual update
__global__ __launch_bounds__(256) void k_update(float* __restrict__ af,
                                                const float* __restrict__ summed,
                                                const float* __restrict__ sc2,
                                                const float* __restrict__ sh2) {
    int idx = blockIdx.x * 256 + threadIdx.x;
    if (idx >= NAT * FEA) return;
    int c = idx & 63;
    float v = af[idx] + summed[idx] * sc2[c] + sh2[c];
    af[idx] = softplus_f(v);
}

// ---------------- fc on selected rows + mask
__global__ __launch_bounds__(256) void k_fc(const float* __restrict__ af,
                                            const int* __restrict__ sel,
                                            const float* __restrict__ mask,
                                            const float* __restrict__ W,
                                            const float* __restrict__ bias,
                                            float* __restrict__ out) {
    __shared__ float A[16][64];
    int tid = threadIdx.x;
    int r0 = blockIdx.x * 16;
    for (int t = tid; t < 16 * 64; t += 256) {
        int r = t >> 6, k = t & 63;
        int n = sel[r0 + r];
        A[r][k] = af[(size_t)n * FEA + k];
    }
    __syncthreads();
    float acc[16][3];
    #pragma unroll
    for (int r = 0; r < 16; ++r) { acc[r][0] = 0.f; acc[r][1] = 0.f; acc[r][2] = 0.f; }
    for (int k = 0; k < 64; ++k) {
        float w0 = W[(size_t)k * HIDD + tid];
        float w1 = W[(size_t)k * HIDD + 256 + tid];
        float w2 = W[(size_t)k * HIDD + 512 + tid];
        #pragma unroll
        for (int r = 0; r < 16; ++r) {
            float a = A[r][k];
            acc[r][0] = fmaf(a, w0, acc[r][0]);
            acc[r][1] = fmaf(a, w1, acc[r][1]);
            acc[r][2] = fmaf(a, w2, acc[r][2]);
        }
    }
    float b0 = bias[tid], b1 = bias[256 + tid], b2 = bias[512 + tid];
    #pragma unroll
    for (int r = 0; r < 16; ++r) {
        float mv = mask[r0 + r];
        size_t base = (size_t)(r0 + r) * HIDD;
        out[base + tid] = (acc[r][0] + b0) * mv;
        out[base + 256 + tid] = (acc[r][1] + b1) * mv;
        out[base + 512 + tid] = (acc[r][2] + b2) * mv;
    }
}

__global__ __launch_bounds__(256) void k_mask(const float* __restrict__ mask,
                                              float* __restrict__ out) {
    int idx = blockIdx.x * 256 + threadIdx.x;
    if (idx < BB * LL) out[(size_t)BB * LL * HIDD + idx] = mask[idx];
}

// ---------------------------------------------------------------- launch
extern "C" void kernel_launch(void* const* d_in, const int* in_sizes, int n_in,
                              void* d_out, int out_size, void* d_ws, size_t ws_size,
                              hipStream_t stream) {
    const int* atom_num  = (const int*)d_in[0];
    const int* nbr_idx   = (const int*)d_in[1];
    const float* nbr_fea = (const float*)d_in[2];
    const int* sel_idx   = (const int*)d_in[3];
    const float* mask    = (const float*)d_in[4];
    const float* emb     = (const float*)d_in[5];
    const float* conv_W  = (const float*)d_in[6];
    const float* conv_b  = (const float*)d_in[7];
    const float* bn1_g   = (const float*)d_in[8];
    const float* bn1_b   = (const float*)d_in[9];
    const float* bn2_g   = (const float*)d_in[10];
    const float* bn2_b   = (const float*)d_in[11];
    const float* fc_W    = (const float*)d_in[12];
    const float* fc_b    = (const float*)d_in[13];
    float* out = (float*)d_out;

    char* p = (char*)d_ws;
    float* af = (float*)p;                 p += (size_t)NAT * FEA * 4;
    unsigned short* S16 = (unsigned short*)p; p += (size_t)NAT * C2 * 2;
    unsigned short* T16 = (unsigned short*)p; p += (size_t)NAT * C2 * 2;
    float* summed = (float*)p;             p += (size_t)NAT * FEA * 4;
    float* psum = (float*)p;               p += (size_t)C2 * CONV_BLKS * 4;
    float* psq = (float*)p;                p += (size_t)C2 * CONV_BLKS * 4;
    float* sc1 = (float*)p;                p += C2 * 4;
    float* sh1 = (float*)p;                p += C2 * 4;
    float* sc2 = (float*)p;                p += FEA * 4;
    float* sh2 = (float*)p;                p += FEA * 4;

    k_embed<<<(NAT * FEA + 255) / 256, 256, 0, stream>>>(atom_num, emb, af);

    for (int i = 0; i < NCONV; ++i) {
        const float* Wb = conv_W + (size_t)i * 169 * C2;
        k_st<<<NAT / 16, 256, 0, stream>>>(af, Wb, conv_b + i * C2, S16, T16);
        k_conv<0><<<CONV_BLKS, 256, 0, stream>>>(S16, T16, nbr_fea, nbr_idx, Wb,
                                                 nullptr, nullptr, nullptr, psum, psq);
        k_bnfin<<<C2, 256, 0, stream>>>(psum, psq, bn1_g + i * C2, bn1_b + i * C2,
                                        1.f / (float)(NAT * (long)MNB), sc1, sh1);
        k_conv<1><<<CONV_BLKS, 256, 0, stream>>>(S16, T16, nbr_fea, nbr_idx, Wb,
                                                 sc1, sh1, summed, psum, psq);
        k_bnfin<<<FEA, 256, 0, stream>>>(psum, psq, bn2_g + i * FEA, bn2_b + i * FEA,
                                         1.f / (float)NAT, sc2, sh2);
        k_update<<<(NAT * FEA + 255) / 256, 256, 0, stream>>>(af, summed, sc2, sh2);
    }

    k_fc<<<BB * LL / 16, 256, 0, stream>>>(af, sel_idx, mask, fc_W, fc_b, out);
    k_mask<<<(BB * LL + 255) / 256, 256, 0, stream>>>(mask, out);
}

// Round 3
// 3295.615 us; speedup vs baseline: 1.3343x; 1.3343x over previous
//
#include <hip/hip_runtime.h>
#include <math.h>

#define NAT 100000
#define MNB 12
#define FEA 64
#define NBRF 41
#define C2 128
#define HIDD 768
#define NCONV 3
#define BB 32
#define LL 512
#define EPSV 1e-5f
#define SPW 8                  // samples per wave in k_conv
#define CB2 (NAT / (4 * SPW))  // 3125 conv blocks

typedef short bf16x8 __attribute__((ext_vector_type(8)));
typedef float f32x4 __attribute__((ext_vector_type(4)));

__device__ __forceinline__ float softplus_f(float x) {
    if (x > 20.f) return x;
    return log1pf(__expf(x));
}
__device__ __forceinline__ float sigmoid_f(float x) {
    return 1.f / (1.f + __expf(-x));
}
__device__ __forceinline__ unsigned short f2bf(float x) {
    union { float f; unsigned u; } v; v.f = x;
    unsigned r = v.u + 0x7fff + ((v.u >> 16) & 1);
    return (unsigned short)(r >> 16);
}
__device__ __forceinline__ float bf2f(unsigned short u) {
    union { unsigned u; float f; } v; v.u = ((unsigned)u) << 16; return v.f;
}

// ---------------------------------------------------------------- embed
__global__ __launch_bounds__(256) void k_embed(const int* __restrict__ anum,
                                               const float* __restrict__ emb,
                                               float* __restrict__ af) {
    int idx = blockIdx.x * 256 + threadIdx.x;
    if (idx >= NAT * FEA) return;
    int n = idx >> 6, c = idx & 63;
    af[idx] = emb[anum[n] * FEA + c];
}

// ---------------- one-time: nbr_fea -> bf16, padded fragment layout
// Apad[sample][kbg(6)][row(16)][8]  (row>=12 or k>=41 -> 0)
__global__ __launch_bounds__(256) void k_prepad(const float* __restrict__ nf,
                                                unsigned short* __restrict__ Apad) {
    int t = blockIdx.x * 256 + threadIdx.x;       // group index, 0 .. NAT*96-1
    if (t >= NAT * 96) return;
    int row = t & 15;
    int q = t >> 4;            // sample*6 + kbg
    int kbg = q % 6;
    int sample = q / 6;
    int k0 = kbg * 8;
    short vv[8];
    if (row < 12) {
        const float* src = nf + ((size_t)sample * MNB + row) * NBRF;
        #pragma unroll
        for (int j = 0; j < 8; ++j) {
            int k = k0 + j;
            vv[j] = (k < NBRF) ? (short)f2bf(src[k]) : (short)0;
        }
    } else {
        #pragma unroll
        for (int j = 0; j < 8; ++j) vv[j] = 0;
    }
    bf16x8 pack = {vv[0], vv[1], vv[2], vv[3], vv[4], vv[5], vv[6], vv[7]};
    *(bf16x8*)(Apad + (size_t)t * 8) = pack;
}

// ---------------- per-layer: W[128:169] -> bf16 B-fragments, permuted cols
// Wfrag linear idx = ct*1024 + s*512 + kb*128 + col*8 + j ; channel = col*8+ct
__global__ __launch_bounds__(256) void k_wfrag(const float* __restrict__ Wb,
                                               unsigned short* __restrict__ Wfrag) {
    int idx = blockIdx.x * 256 + threadIdx.x;
    if (idx >= 8192) return;
    int j = idx & 7;
    int col = (idx >> 3) & 15;
    int kb = (idx >> 7) & 3;
    int s = (idx >> 9) & 1;
    int ct = idx >> 10;
    int k = s * 32 + kb * 8 + j;
    int ch = col * 8 + ct;
    float v = (k < NBRF) ? Wb[(size_t)(C2 + k) * C2 + ch] : 0.f;
    Wfrag[idx] = f2bf(v);
}

// ---------------- S = af@W[0:64]+b (bf16), T = af@W[64:128] (bf16)
__global__ __launch_bounds__(256) void k_st(const float* __restrict__ af,
                                            const float* __restrict__ Wb,
                                            const float* __restrict__ bb,
                                            unsigned short* __restrict__ S16,
                                            unsigned short* __restrict__ T16) {
    __shared__ float Ws[64][128];
    __shared__ float As[16][65];
    int tid = threadIdx.x;
    int a0 = blockIdx.x * 16;
    for (int t = tid; t < 16 * 64; t += 256) {
        int a = t >> 6, k = t & 63;
        As[a][k] = af[(size_t)(a0 + a) * FEA + k];
    }
    int a = tid >> 4, c0 = tid & 15;
    int n = a0 + a;
    for (int half = 0; half < 2; ++half) {
        __syncthreads();
        for (int t = tid; t < 64 * 128; t += 256) {
            int k = t >> 7, c = t & 127;
            Ws[k][c] = Wb[(size_t)(half * 64 + k) * C2 + c];
        }
        __syncthreads();
        float acc[8];
        #pragma unroll
        for (int j = 0; j < 8; ++j) acc[j] = 0.f;
        for (int k = 0; k < 64; ++k) {
            float av = As[a][k];
            #pragma unroll
            for (int j = 0; j < 8; ++j)
                acc[j] = fmaf(av, Ws[k][c0 + j * 16], acc[j]);
        }
        if (half == 0) {
            #pragma unroll
            for (int j = 0; j < 8; ++j) {
                int c = c0 + j * 16;
                S16[(size_t)n * C2 + c] = f2bf(acc[j] + bb[c]);
            }
        } else {
            #pragma unroll
            for (int j = 0; j < 8; ++j)
                T16[(size_t)n * C2 + c0 + j * 16] = f2bf(acc[j]);
        }
    }
}

// ---------------- fused conv pass, fragment-direct loads
// MODE 0: BN1 stats over gated (128 ch). MODE 1: BN1 apply+gate+m-sum; BN2 stats.
template<int MODE>
__global__ __launch_bounds__(256) void k_conv(const unsigned short* __restrict__ Apad,
                                              const unsigned short* __restrict__ Wfrag,
                                              const unsigned short* __restrict__ S16,
                                              const unsigned short* __restrict__ T16,
                                              const int* __restrict__ nidx,
                                              const float* __restrict__ sc1,
                                              const float* __restrict__ sh1,
                                              float* __restrict__ summed,
                                              float* __restrict__ psum,
                                              float* __restrict__ psq) {
    __shared__ float red1[4][C2];
    __shared__ float red2[4][C2];
    int tid = threadIdx.x;
    int w = tid >> 6, l = tid & 63;
    int c_loc = l & 15, kg = l >> 4;
    const bf16x8 zero8 = {0, 0, 0, 0, 0, 0, 0, 0};

    // hoist all 16 B fragments (wave-invariant, L2-resident)
    const bf16x8* wf = (const bf16x8*)Wfrag;
    bf16x8 bfr[16];
    #pragma unroll
    for (int f = 0; f < 16; ++f) bfr[f] = wf[f * 64 + l];

    float sc1v[8], sh1v[8];
    if (MODE == 1) {
        #pragma unroll
        for (int ct = 0; ct < 8; ++ct) {
            sc1v[ct] = sc1[c_loc * 8 + ct];
            sh1v[ct] = sh1[c_loc * 8 + ct];
        }
    }

    float sA[8], sB[8];
    #pragma unroll
    for (int i = 0; i < 8; ++i) { sA[i] = 0.f; sB[i] = 0.f; }

    int sbase = (blockIdx.x * 4 + w) * SPW;
    int r0 = (kg < 3) ? kg * 4 : 0;   // first valid m-row for this lane's kg

    // prefetch sample 0
    const bf16x8* ap = (const bf16x8*)(Apad + (size_t)sbase * 768);
    bf16x8 a0 = ap[l];
    bf16x8 a1 = (kg < 2) ? ap[64 + l] : zero8;
    bf16x8 sv = *(const bf16x8*)(S16 + (size_t)sbase * C2 + c_loc * 8);
    int j0 = nidx[sbase * MNB + r0];
    int j1 = nidx[sbase * MNB + ((kg < 3) ? r0 + 1 : 0)];
    int j2 = nidx[sbase * MNB + ((kg < 3) ? r0 + 2 : 0)];
    int j3 = nidx[sbase * MNB + ((kg < 3) ? r0 + 3 : 0)];

    for (int si = 0; si < SPW; ++si) {
        int n = sbase + si;
        // issue T row loads early (hidden under MFMA)
        bf16x8 t0 = zero8, t1 = zero8, t2 = zero8, t3 = zero8;
        if (kg < 3) {
            t0 = *(const bf16x8*)(T16 + (size_t)j0 * C2 + c_loc * 8);
            t1 = *(const bf16x8*)(T16 + (size_t)j1 * C2 + c_loc * 8);
            t2 = *(const bf16x8*)(T16 + (size_t)j2 * C2 + c_loc * 8);
            t3 = *(const bf16x8*)(T16 + (size_t)j3 * C2 + c_loc * 8);
        }

        f32x4 acc[8];
        #pragma unroll
        for (int ct = 0; ct < 8; ++ct) {
            acc[ct] = f32x4{0.f, 0.f, 0.f, 0.f};
            acc[ct] = __builtin_amdgcn_mfma_f32_16x16x32_bf16(a0, bfr[ct * 2 + 0], acc[ct], 0, 0, 0);
            acc[ct] = __builtin_amdgcn_mfma_f32_16x16x32_bf16(a1, bfr[ct * 2 + 1], acc[ct], 0, 0, 0);
        }

        float Sv[8];
        #pragma unroll
        for (int ct = 0; ct < 8; ++ct) Sv[ct] = bf2f((unsigned short)sv[ct]);

        // prefetch next sample
        bf16x8 na0 = a0, na1 = a1, nsv = sv;
        int nj0 = j0, nj1 = j1, nj2 = j2, nj3 = j3;
        if (si + 1 < SPW) {
            const bf16x8* ap2 = ap + 96;
            na0 = ap2[l];
            na1 = (kg < 2) ? ap2[64 + l] : zero8;
            nsv = *(const bf16x8*)(S16 + (size_t)(n + 1) * C2 + c_loc * 8);
            int nb = (n + 1) * MNB;
            nj0 = nidx[nb + r0];
            nj1 = nidx[nb + ((kg < 3) ? r0 + 1 : 0)];
            nj2 = nidx[nb + ((kg < 3) ? r0 + 2 : 0)];
            nj3 = nidx[nb + ((kg < 3) ? r0 + 3 : 0)];
        }

        if (MODE == 0) {
            if (kg < 3) {
                #pragma unroll
                for (int i = 0; i < 4; ++i) {
                    bf16x8 tv = (i == 0) ? t0 : (i == 1) ? t1 : (i == 2) ? t2 : t3;
                    #pragma unroll
                    for (int ct = 0; ct < 8; ++ct) {
                        float g = acc[ct][i] + Sv[ct] + bf2f((unsigned short)tv[ct]);
                        sA[ct] += g; sB[ct] += g * g;
                    }
                }
            }
        } else {
            float vs[8];
            #pragma unroll
            for (int ct = 0; ct < 8; ++ct) vs[ct] = 0.f;
            #pragma unroll
            for (int i = 0; i < 4; ++i) {
                bf16x8 tv = (i == 0) ? t0 : (i == 1) ? t1 : (i == 2) ? t2 : t3;
                float g[8];
                #pragma unroll
                for (int ct = 0; ct < 8; ++ct)
                    g[ct] = (acc[ct][i] + Sv[ct] + bf2f((unsigned short)tv[ct])) * sc1v[ct] + sh1v[ct];
                #pragma unroll
                for (int ct = 0; ct < 8; ++ct) {
                    float gp = __shfl_xor(g[ct], 8);
                    float p = sigmoid_f(g[ct]) * softplus_f(gp);
                    if (kg < 3) vs[ct] += p;
                }
            }
            #pragma unroll
            for (int ct = 0; ct < 8; ++ct) {
                vs[ct] += __shfl_xor(vs[ct], 16);
                vs[ct] += __shfl_xor(vs[ct], 32);
            }
            if (l < 8) {
                float4 o0 = {vs[0], vs[1], vs[2], vs[3]};
                float4 o1 = {vs[4], vs[5], vs[6], vs[7]};
                *(float4*)(summed + (size_t)n * FEA + l * 8) = o0;
                *(float4*)(summed + (size_t)n * FEA + l * 8 + 4) = o1;
                #pragma unroll
                for (int ct = 0; ct < 8; ++ct) {
                    sA[ct] += vs[ct]; sB[ct] += vs[ct] * vs[ct];
                }
            }
        }

        a0 = na0; a1 = na1; sv = nsv;
        j0 = nj0; j1 = nj1; j2 = nj2; j3 = nj3;
        ap += 96;
    }

    // block-level stats reduction (deterministic)
    if (MODE == 0) {
        #pragma unroll
        for (int ct = 0; ct < 8; ++ct) {
            sA[ct] += __shfl_xor(sA[ct], 16); sA[ct] += __shfl_xor(sA[ct], 32);
            sB[ct] += __shfl_xor(sB[ct], 16); sB[ct] += __shfl_xor(sB[ct], 32);
        }
        if (l < 16) {
            #pragma unroll
            for (int ct = 0; ct < 8; ++ct) {
                red1[w][l * 8 + ct] = sA[ct];
                red2[w][l * 8 + ct] = sB[ct];
            }
        }
        __syncthreads();
        if (tid < C2) {
            float ts = red1[0][tid] + red1[1][tid] + red1[2][tid] + red1[3][tid];
            float tq = red2[0][tid] + red2[1][tid] + red2[2][tid] + red2[3][tid];
            psum[(size_t)tid * CB2 + blockIdx.x] = ts;
            psq[(size_t)tid * CB2 + blockIdx.x] = tq;
        }
    } else {
        if (l < 8) {
            #pragma unroll
            for (int ct = 0; ct < 8; ++ct) {
                red1[w][l * 8 + ct] = sA[ct];
                red2[w][l * 8 + ct] = sB[ct];
            }
        }
        __syncthreads();
        if (tid < FEA) {
            float ts = red1[0][tid] + red1[1][tid] + red1[2][tid] + red1[3][tid];
            float tq = red2[0][tid] + red2[1][tid] + red2[2][tid] + red2[3][tid];
            psum[(size_t)tid * CB2 + blockIdx.x] = ts;
            psq[(size_t)tid * CB2 + blockIdx.x] = tq;
        }
    }
}

// ---------------- BN finalize
__global__ __launch_bounds__(256) void k_bnfin(const float* __restrict__ psum,
                                               const float* __restrict__ psq,
                                               const float* __restrict__ g,
                                               const float* __restrict__ b,
                                               float cnt_inv,
                                               float* __restrict__ scale,
                                               float* __restrict__ shift) {
    int c = blockIdx.x;
    int tid = threadIdx.x;
    __shared__ float r1[256], r2[256];
    float s = 0.f, q = 0.f;
    for (int t = tid; t < CB2; t += 256) {
        s += psum[(size_t)c * CB2 + t];
        q += psq[(size_t)c * CB2 + t];
    }
    r1[tid] = s; r2[tid] = q;
    __syncthreads();
    for (int st = 128; st > 0; st >>= 1) {
        if (tid < st) { r1[tid] += r1[tid + st]; r2[tid] += r2[tid + st]; }
        __syncthreads();
    }
    if (tid == 0) {
        float mean = r1[0] * cnt_inv;
        float var = r2[0] * cnt_inv - mean * mean;
        float sc = g[c] * rsqrtf(var + EPSV);
        scale[c] = sc;
        shift[c] = b[c] - mean * sc;
    }
}

// ---------------- residual update
__global__ __launch_bounds__(256) void k_update(float* __restrict__ af,
                                                const float* __restrict__ summed,
                                                const float* __restrict__ sc2,
                                                const float* __restrict__ sh2) {
    int idx = blockIdx.x * 256 + threadIdx.x;
    if (idx >= NAT * FEA) return;
    int c = idx & 63;
    float v = af[idx] + summed[idx] * sc2[c] + sh2[c];
    af[idx] = softplus_f(v);
}

// ---------------- fc on selected rows + mask
__global__ __launch_bounds__(256) void k_fc(const float* __restrict__ af,
                                            const int* __restrict__ sel,
                                            const float* __restrict__ mask,
                                            const float* __restrict__ W,
                                            const float* __restrict__ bias,
                                            float* __restrict__ out) {
    __shared__ float A[16][64];
    int tid = threadIdx.x;
    int r0 = blockIdx.x * 16;
    for (int t = tid; t < 16 * 64; t += 256) {
        int r = t >> 6, k = t & 63;
        int n = sel[r0 + r];
        A[r][k] = af[(size_t)n * FEA + k];
    }
    __syncthreads();
    float acc[16][3];
    #pragma unroll
    for (int r = 0; r < 16; ++r) { acc[r][0] = 0.f; acc[r][1] = 0.f; acc[r][2] = 0.f; }
    for (int k = 0; k < 64; ++k) {
        float w0 = W[(size_t)k * HIDD + tid];
        float w1 = W[(size_t)k * HIDD + 256 + tid];
        float w2 = W[(size_t)k * HIDD + 512 + tid];
        #pragma unroll
        for (int r = 0; r < 16; ++r) {
            float a = A[r][k];
            acc[r][0] = fmaf(a, w0, acc[r][0]);
            acc[r][1] = fmaf(a, w1, acc[r][1]);
            acc[r][2] = fmaf(a, w2, acc[r][2]);
        }
    }
    float b0 = bias[tid], b1 = bias[256 + tid], b2 = bias[512 + tid];
    #pragma unroll
    for (int r = 0; r < 16; ++r) {
        float mv = mask[r0 + r];
        size_t base = (size_t)(r0 + r) * HIDD;
        out[base + tid] = (acc[r][0] + b0) * mv;
        out[base + 256 + tid] = (acc[r][1] + b1) * mv;
        out[base + 512 + tid] = (acc[r][2] + b2) * mv;
    }
}

__global__ __launch_bounds__(256) void k_mask(const float* __restrict__ mask,
                                              float* __restrict__ out) {
    int idx = blockIdx.x * 256 + threadIdx.x;
    if (idx < BB * LL) out[(size_t)BB * LL * HIDD + idx] = mask[idx];
}

// ---------------------------------------------------------------- launch
extern "C" void kernel_launch(void* const* d_in, const int* in_sizes, int n_in,
                              void* d_out, int out_size, void* d_ws, size_t ws_size,
                              hipStream_t stream) {
    const int* atom_num  = (const int*)d_in[0];
    const int* nbr_idx   = (const int*)d_in[1];
    const float* nbr_fea = (const float*)d_in[2];
    const int* sel_idx   = (const int*)d_in[3];
    const float* mask    = (const float*)d_in[4];
    const float* emb     = (const float*)d_in[5];
    const float* conv_W  = (const float*)d_in[6];
    const float* conv_b  = (const float*)d_in[7];
    const float* bn1_g   = (const float*)d_in[8];
    const float* bn1_b   = (const float*)d_in[9];
    const float* bn2_g   = (const float*)d_in[10];
    const float* bn2_b   = (const float*)d_in[11];
    const float* fc_W    = (const float*)d_in[12];
    const float* fc_b    = (const float*)d_in[13];
    float* out = (float*)d_out;

    char* p = (char*)d_ws;
    float* af = (float*)p;                    p += (size_t)NAT * FEA * 4;
    unsigned short* S16 = (unsigned short*)p; p += (size_t)NAT * C2 * 2;
    unsigned short* T16 = (unsigned short*)p; p += (size_t)NAT * C2 * 2;
    float* summed = (float*)p;                p += (size_t)NAT * FEA * 4;
    float* psum = (float*)p;                  p += (size_t)C2 * CB2 * 4;
    float* psq = (float*)p;                   p += (size_t)C2 * CB2 * 4;
    float* sc1 = (float*)p;                   p += 512;
    float* sh1 = (float*)p;                   p += 512;
    float* sc2 = (float*)p;                   p += 512;
    float* sh2 = (float*)p;                   p += 512;
    unsigned short* Wfrag = (unsigned short*)p; p += 16384;
    unsigned short* Apad = (unsigned short*)p;  p += (size_t)NAT * 768 * 2;

    k_embed<<<(NAT * FEA) / 256, 256, 0, stream>>>(atom_num, emb, af);
    k_prepad<<<(NAT * 96) / 256, 256, 0, stream>>>(nbr_fea, Apad);

    for (int i = 0; i < NCONV; ++i) {
        const float* Wb = conv_W + (size_t)i * 169 * C2;
        k_wfrag<<<32, 256, 0, stream>>>(Wb, Wfrag);
        k_st<<<NAT / 16, 256, 0, stream>>>(af, Wb, conv_b + i * C2, S16, T16);
        k_conv<0><<<CB2, 256, 0, stream>>>(Apad, Wfrag, S16, T16, nbr_idx,
                                           sc1, sh1, summed, psum, psq);
        k_bnfin<<<C2, 256, 0, stream>>>(psum, psq, bn1_g + i * C2, bn1_b + i * C2,
                                        1.f / (float)(NAT * (long)MNB), sc1, sh1);
        k_conv<1><<<CB2, 256, 0, stream>>>(Apad, Wfrag, S16, T16, nbr_idx,
                                           sc1, sh1, summed, psum, psq);
        k_bnfin<<<FEA, 256, 0, stream>>>(psum, psq, bn2_g + i * FEA, bn2_b + i * FEA,
                                         1.f / (float)NAT, sc2, sh2);
        k_update<<<(NAT * FEA) / 256, 256, 0, stream>>>(af, summed, sc2, sh2);
    }

    k_fc<<<BB * LL / 16, 256, 0, stream>>>(af, sel_idx, mask, fc_W, fc_b, out);
    k_mask<<<(BB * LL + 255) / 256, 256, 0, stream>>>(mask, out);
}

// Round 4
// 1271.059 us; speedup vs baseline: 3.4595x; 2.5928x over previous
//
#include <hip/hip_runtime.h>
#include <math.h>

#define NAT 100000
#define MNB 12
#define FEA 64
#define NBRF 41
#define C2 128
#define HIDD 768
#define NCONV 3
#define BB 32
#define LL 512
#define EPSV 1e-5f
#define SPB 16                 // samples per block in k_conv
#define CB (NAT / SPB)         // 6250 conv blocks

typedef short bf16x8 __attribute__((ext_vector_type(8)));
typedef float f32x4 __attribute__((ext_vector_type(4)));

__device__ __forceinline__ float fsig(float x) {
    float e = __expf(-x);
    return __builtin_amdgcn_rcpf(1.f + e);
}
__device__ __forceinline__ float fsp(float x) {
    float e = __expf(x);
    float l = __logf(1.f + e);
    return (x > 20.f) ? x : l;
}
__device__ __forceinline__ unsigned short f2bf(float x) {
    union { float f; unsigned u; } v; v.f = x;
    unsigned r = v.u + 0x7fff + ((v.u >> 16) & 1);
    return (unsigned short)(r >> 16);
}
__device__ __forceinline__ float bf2f(unsigned short u) {
    union { unsigned u; float f; } v; v.u = ((unsigned)u) << 16; return v.f;
}

// ---------------------------------------------------------------- embed
__global__ __launch_bounds__(256) void k_embed(const int* __restrict__ anum,
                                               const float* __restrict__ emb,
                                               float* __restrict__ af) {
    int idx = blockIdx.x * 256 + threadIdx.x;
    if (idx >= NAT * FEA) return;
    int n = idx >> 6, c = idx & 63;
    af[idx] = emb[anum[n] * FEA + c];
}

// ---------------- one-time: nbr_fea -> bf16 padded fragment layout
// Apad[sample][kbg(6)][row(16)][8]  (row>=12 or k>=41 -> 0); 1.5KB/sample
__global__ __launch_bounds__(256) void k_prepad(const float* __restrict__ nf,
                                                unsigned short* __restrict__ Apad) {
    int t = blockIdx.x * 256 + threadIdx.x;
    if (t >= NAT * 96) return;
    int row = t & 15;
    int q = t >> 4;
    int kbg = q % 6;
    int sample = q / 6;
    int k0 = kbg * 8;
    short vv[8];
    if (row < 12) {
        const float* src = nf + ((size_t)sample * MNB + row) * NBRF;
        #pragma unroll
        for (int j = 0; j < 8; ++j) {
            int k = k0 + j;
            vv[j] = (k < NBRF) ? (short)f2bf(src[k]) : (short)0;
        }
    } else {
        #pragma unroll
        for (int j = 0; j < 8; ++j) vv[j] = 0;
    }
    bf16x8 pack = {vv[0], vv[1], vv[2], vv[3], vv[4], vv[5], vv[6], vv[7]};
    *(bf16x8*)(Apad + (size_t)t * 8) = pack;
}

// ---------------- per-layer: B-fragments, wave-sliced channel mapping
// frag idx = ((w*2+ct)*2+kk)*512 + lane*8 + j
// lane=(c_loc,kg): k = kk*32 + kg*8 + j ; ch = ct==0 ? w*16+c_loc : 64+w*16+c_loc
__global__ __launch_bounds__(256) void k_wfrag(const float* __restrict__ Wb,
                                               unsigned short* __restrict__ Wfrag) {
    int idx = blockIdx.x * 256 + threadIdx.x;
    if (idx >= 8192) return;
    int j = idx & 7;
    int lane = (idx >> 3) & 63;
    int kk = (idx >> 9) & 1;
    int ct = (idx >> 10) & 1;
    int w = (idx >> 11) & 3;
    int c_loc = lane & 15, kg = lane >> 4;
    int k = kk * 32 + kg * 8 + j;
    int ch = w * 16 + c_loc + (ct ? 64 : 0);
    float v = (k < NBRF) ? Wb[(size_t)(C2 + k) * C2 + ch] : 0.f;
    Wfrag[idx] = f2bf(v);
}

// ---------------- S = af@W[0:64]+b (bf16), T = af@W[64:128] (bf16)
__global__ __launch_bounds__(256) void k_st(const float* __restrict__ af,
                                            const float* __restrict__ Wb,
                                            const float* __restrict__ bb,
                                            unsigned short* __restrict__ S16,
                                            unsigned short* __restrict__ T16) {
    __shared__ float Ws[64][128];
    __shared__ float As[16][65];
    int tid = threadIdx.x;
    int a0 = blockIdx.x * 16;
    for (int t = tid; t < 16 * 64; t += 256) {
        int a = t >> 6, k = t & 63;
        As[a][k] = af[(size_t)(a0 + a) * FEA + k];
    }
    int a = tid >> 4, c0 = tid & 15;
    int n = a0 + a;
    for (int half = 0; half < 2; ++half) {
        __syncthreads();
        for (int t = tid; t < 64 * 128; t += 256) {
            int k = t >> 7, c = t & 127;
            Ws[k][c] = Wb[(size_t)(half * 64 + k) * C2 + c];
        }
        __syncthreads();
        float acc[8];
        #pragma unroll
        for (int j = 0; j < 8; ++j) acc[j] = 0.f;
        for (int k = 0; k < 64; ++k) {
            float av = As[a][k];
            #pragma unroll
            for (int j = 0; j < 8; ++j)
                acc[j] = fmaf(av, Ws[k][c0 + j * 16], acc[j]);
        }
        if (half == 0) {
            #pragma unroll
            for (int j = 0; j < 8; ++j) {
                int c = c0 + j * 16;
                S16[(size_t)n * C2 + c] = f2bf(acc[j] + bb[c]);
            }
        } else {
            #pragma unroll
            for (int j = 0; j < 8; ++j)
                T16[(size_t)n * C2 + c0 + j * 16] = f2bf(acc[j]);
        }
    }
}

// ---------------- fused conv pass: lean-register wave-sliced version
// MODE 0: BN1 stats (128 ch). MODE 1: BN1 apply + gate + m-sum + BN2 stats (64 ch).
template<int MODE>
__global__ __launch_bounds__(256) void k_conv(const unsigned short* __restrict__ Apad,
                                              const unsigned short* __restrict__ Wfrag,
                                              const unsigned short* __restrict__ S16,
                                              const unsigned short* __restrict__ T16,
                                              const int* __restrict__ nidx,
                                              const float* __restrict__ sc1,
                                              const float* __restrict__ sh1,
                                              float* __restrict__ summed,
                                              float* __restrict__ psum,
                                              float* __restrict__ psq) {
    __shared__ __align__(16) unsigned short As[SPB * 768];   // 24KB
    __shared__ __align__(16) int NIl[SPB * 16];              // 1KB
    int tid = threadIdx.x;
    int w = tid >> 6, l = tid & 63;
    int c_loc = l & 15, kg = l >> 4;
    int blk = blockIdx.x;
    size_t s0 = (size_t)blk * SPB;

    // stage A tiles (coalesced 16B copies) + padded neighbor indices
    const unsigned short* agbase = Apad + s0 * 768;
    #pragma unroll
    for (int r = 0; r < 6; ++r) {
        int t = r * 256 + tid;
        *(bf16x8*)&As[t * 8] = *(const bf16x8*)&agbase[t * 8];
    }
    {
        int s = tid >> 4, c = tid & 15;
        NIl[tid] = (c < 12) ? nidx[(s0 + s) * MNB + c] : 0;
    }

    // per-wave B fragments (4 x 16B, wave-invariant)
    const bf16x8* wf = (const bf16x8*)(Wfrag + (size_t)w * 2048);
    bf16x8 bF0 = wf[0 * 64 + l];
    bf16x8 bF1 = wf[1 * 64 + l];
    bf16x8 bC0 = wf[2 * 64 + l];
    bf16x8 bC1 = wf[3 * 64 + l];

    int chF = w * 16 + c_loc;
    int chC = chF + 64;
    float scF, shF, scC, shC;
    if (MODE == 1) {
        scF = sc1[chF]; shF = sh1[chF];
        scC = sc1[chC]; shC = sh1[chC];
    }

    float sA0 = 0.f, sA1 = 0.f, sB0 = 0.f, sB1 = 0.f;
    __syncthreads();

    for (int si = 0; si < SPB; ++si) {
        size_t n = s0 + si;
        bf16x8 a0 = *(const bf16x8*)&As[si * 768 + kg * 128 + c_loc * 8];
        bf16x8 a1 = {0, 0, 0, 0, 0, 0, 0, 0};
        if (kg < 2) a1 = *(const bf16x8*)&As[si * 768 + (4 + kg) * 128 + c_loc * 8];
        int4 jr = *(const int4*)&NIl[si * 16 + kg * 4];

        float Tf[4] = {0.f, 0.f, 0.f, 0.f}, Tc[4] = {0.f, 0.f, 0.f, 0.f};
        float Sf = 0.f, Sc = 0.f;
        if (kg < 3) {
            Tf[0] = bf2f(T16[(size_t)jr.x * C2 + chF]);
            Tf[1] = bf2f(T16[(size_t)jr.y * C2 + chF]);
            Tf[2] = bf2f(T16[(size_t)jr.z * C2 + chF]);
            Tf[3] = bf2f(T16[(size_t)jr.w * C2 + chF]);
            Tc[0] = bf2f(T16[(size_t)jr.x * C2 + chC]);
            Tc[1] = bf2f(T16[(size_t)jr.y * C2 + chC]);
            Tc[2] = bf2f(T16[(size_t)jr.z * C2 + chC]);
            Tc[3] = bf2f(T16[(size_t)jr.w * C2 + chC]);
            Sf = bf2f(S16[n * C2 + chF]);
            Sc = bf2f(S16[n * C2 + chC]);
        }

        f32x4 aF = {0.f, 0.f, 0.f, 0.f};
        f32x4 aC = {0.f, 0.f, 0.f, 0.f};
        aF = __builtin_amdgcn_mfma_f32_16x16x32_bf16(a0, bF0, aF, 0, 0, 0);
        aF = __builtin_amdgcn_mfma_f32_16x16x32_bf16(a1, bF1, aF, 0, 0, 0);
        aC = __builtin_amdgcn_mfma_f32_16x16x32_bf16(a0, bC0, aC, 0, 0, 0);
        aC = __builtin_amdgcn_mfma_f32_16x16x32_bf16(a1, bC1, aC, 0, 0, 0);

        if (MODE == 0) {
            if (kg < 3) {
                #pragma unroll
                for (int r = 0; r < 4; ++r) {
                    float gF = aF[r] + Sf + Tf[r];
                    float gC = aC[r] + Sc + Tc[r];
                    sA0 += gF; sB0 += gF * gF;
                    sA1 += gC; sB1 += gC * gC;
                }
            }
        } else {
            float vs = 0.f;
            if (kg < 3) {
                #pragma unroll
                for (int r = 0; r < 4; ++r) {
                    float gF = (aF[r] + Sf + Tf[r]) * scF + shF;
                    float gC = (aC[r] + Sc + Tc[r]) * scC + shC;
                    vs += fsig(gF) * fsp(gC);
                }
            }
            vs += __shfl_xor(vs, 16);
            vs += __shfl_xor(vs, 32);
            if (l < 16) summed[n * FEA + chF] = vs;
            sA0 += vs; sB0 += vs * vs;
        }
    }

    if (MODE == 0) {
        sA0 += __shfl_xor(sA0, 16); sA0 += __shfl_xor(sA0, 32);
        sB0 += __shfl_xor(sB0, 16); sB0 += __shfl_xor(sB0, 32);
        sA1 += __shfl_xor(sA1, 16); sA1 += __shfl_xor(sA1, 32);
        sB1 += __shfl_xor(sB1, 16); sB1 += __shfl_xor(sB1, 32);
        if (l < 16) {
            psum[(size_t)chF * CB + blk] = sA0;
            psq [(size_t)chF * CB + blk] = sB0;
            psum[(size_t)chC * CB + blk] = sA1;
            psq [(size_t)chC * CB + blk] = sB1;
        }
    } else {
        if (l < 16) {
            psum[(size_t)chF * CB + blk] = sA0;
            psq [(size_t)chF * CB + blk] = sB0;
        }
    }
}

// ---------------- BN finalize
__global__ __launch_bounds__(256) void k_bnfin(const float* __restrict__ psum,
                                               const float* __restrict__ psq,
                                               const float* __restrict__ g,
                                               const float* __restrict__ b,
                                               float cnt_inv,
                                               float* __restrict__ scale,
                                               float* __restrict__ shift) {
    int c = blockIdx.x;
    int tid = threadIdx.x;
    __shared__ float r1[256], r2[256];
    float s = 0.f, q = 0.f;
    for (int t = tid; t < CB; t += 256) {
        s += psum[(size_t)c * CB + t];
        q += psq[(size_t)c * CB + t];
    }
    r1[tid] = s; r2[tid] = q;
    __syncthreads();
    for (int st = 128; st > 0; st >>= 1) {
        if (tid < st) { r1[tid] += r1[tid + st]; r2[tid] += r2[tid + st]; }
        __syncthreads();
    }
    if (tid == 0) {
        float mean = r1[0] * cnt_inv;
        float var = r2[0] * cnt_inv - mean * mean;
        float sc = g[c] * rsqrtf(var + EPSV);
        scale[c] = sc;
        shift[c] = b[c] - mean * sc;
    }
}

// ---------------- residual update (float4-vectorized)
__global__ __launch_bounds__(256) void k_update(float* __restrict__ af,
                                                const float* __restrict__ summed,
                                                const float* __restrict__ sc2,
                                                const float* __restrict__ sh2) {
    int t = blockIdx.x * 256 + threadIdx.x;
    if (t >= NAT * 16) return;
    float4 v = ((const float4*)af)[t];
    float4 s = ((const float4*)summed)[t];
    int c0 = (t & 15) * 4;
    v.x = fsp(v.x + s.x * sc2[c0 + 0] + sh2[c0 + 0]);
    v.y = fsp(v.y + s.y * sc2[c0 + 1] + sh2[c0 + 1]);
    v.z = fsp(v.z + s.z * sc2[c0 + 2] + sh2[c0 + 2]);
    v.w = fsp(v.w + s.w * sc2[c0 + 3] + sh2[c0 + 3]);
    ((float4*)af)[t] = v;
}

// ---------------- fc on selected rows + mask
__global__ __launch_bounds__(256) void k_fc(const float* __restrict__ af,
                                            const int* __restrict__ sel,
                                            const float* __restrict__ mask,
                                            const float* __restrict__ W,
                                            const float* __restrict__ bias,
                                            float* __restrict__ out) {
    __shared__ float A[16][64];
    int tid = threadIdx.x;
    int r0 = blockIdx.x * 16;
    for (int t = tid; t < 16 * 64; t += 256) {
        int r = t >> 6, k = t & 63;
        int n = sel[r0 + r];
        A[r][k] = af[(size_t)n * FEA + k];
    }
    __syncthreads();
    float acc[16][3];
    #pragma unroll
    for (int r = 0; r < 16; ++r) { acc[r][0] = 0.f; acc[r][1] = 0.f; acc[r][2] = 0.f; }
    for (int k = 0; k < 64; ++k) {
        float w0 = W[(size_t)k * HIDD + tid];
        float w1 = W[(size_t)k * HIDD + 256 + tid];
        float w2 = W[(size_t)k * HIDD + 512 + tid];
        #pragma unroll
        for (int r = 0; r < 16; ++r) {
            float a = A[r][k];
            acc[r][0] = fmaf(a, w0, acc[r][0]);
            acc[r][1] = fmaf(a, w1, acc[r][1]);
            acc[r][2] = fmaf(a, w2, acc[r][2]);
        }
    }
    float b0 = bias[tid], b1 = bias[256 + tid], b2 = bias[512 + tid];
    #pragma unroll
    for (int r = 0; r < 16; ++r) {
        float mv = mask[r0 + r];
        size_t base = (size_t)(r0 + r) * HIDD;
        out[base + tid] = (acc[r][0] + b0) * mv;
        out[base + 256 + tid] = (acc[r][1] + b1) * mv;
        out[base + 512 + tid] = (acc[r][2] + b2) * mv;
    }
}

__global__ __launch_bounds__(256) void k_mask(const float* __restrict__ mask,
                                              float* __restrict__ out) {
    int idx = blockIdx.x * 256 + threadIdx.x;
    if (idx < BB * LL) out[(size_t)BB * LL * HIDD + idx] = mask[idx];
}

// ---------------------------------------------------------------- launch
extern "C" void kernel_launch(void* const* d_in, const int* in_sizes, int n_in,
                              void* d_out, int out_size, void* d_ws, size_t ws_size,
                              hipStream_t stream) {
    const int* atom_num  = (const int*)d_in[0];
    const int* nbr_idx   = (const int*)d_in[1];
    const float* nbr_fea = (const float*)d_in[2];
    const int* sel_idx   = (const int*)d_in[3];
    const float* mask    = (const float*)d_in[4];
    const float* emb     = (const float*)d_in[5];
    const float* conv_W  = (const float*)d_in[6];
    const float* conv_b  = (const float*)d_in[7];
    const float* bn1_g   = (const float*)d_in[8];
    const float* bn1_b   = (const float*)d_in[9];
    const float* bn2_g   = (const float*)d_in[10];
    const float* bn2_b   = (const float*)d_in[11];
    const float* fc_W    = (const float*)d_in[12];
    const float* fc_b    = (const float*)d_in[13];
    float* out = (float*)d_out;

    char* p = (char*)d_ws;
    float* af = (float*)p;                      p += (size_t)NAT * FEA * 4;
    unsigned short* S16 = (unsigned short*)p;   p += (size_t)NAT * C2 * 2;
    unsigned short* T16 = (unsigned short*)p;   p += (size_t)NAT * C2 * 2;
    float* summed = (float*)p;                  p += (size_t)NAT * FEA * 4;
    float* psum = (float*)p;                    p += (size_t)C2 * CB * 4;
    float* psq = (float*)p;                     p += (size_t)C2 * CB * 4;
    float* sc1 = (float*)p;                     p += 512;
    float* sh1 = (float*)p;                     p += 512;
    float* sc2 = (float*)p;                     p += 512;
    float* sh2 = (float*)p;                     p += 512;
    unsigned short* Wfrag = (unsigned short*)p; p += 16384;
    unsigned short* Apad = (unsigned short*)p;  p += (size_t)NAT * 768 * 2;

    k_embed<<<(NAT * FEA) / 256, 256, 0, stream>>>(atom_num, emb, af);
    k_prepad<<<(NAT * 96) / 256, 256, 0, stream>>>(nbr_fea, Apad);

    for (int i = 0; i < NCONV; ++i) {
        const float* Wb = conv_W + (size_t)i * 169 * C2;
        k_wfrag<<<32, 256, 0, stream>>>(Wb, Wfrag);
        k_st<<<NAT / 16, 256, 0, stream>>>(af, Wb, conv_b + i * C2, S16, T16);
        k_conv<0><<<CB, 256, 0, stream>>>(Apad, Wfrag, S16, T16, nbr_idx,
                                          sc1, sh1, summed, psum, psq);
        k_bnfin<<<C2, 256, 0, stream>>>(psum, psq, bn1_g + i * C2, bn1_b + i * C2,
                                        1.f / (float)(NAT * (long)MNB), sc1, sh1);
        k_conv<1><<<CB, 256, 0, stream>>>(Apad, Wfrag, S16, T16, nbr_idx,
                                          sc1, sh1, summed, psum, psq);
        k_bnfin<<<FEA, 256, 0, stream>>>(psum, psq, bn2_g + i * FEA, bn2_b + i * FEA,
                                         1.f / (float)NAT, sc2, sh2);
        k_update<<<(NAT * 16) / 256, 256, 0, stream>>>(af, summed, sc2, sh2);
    }

    k_fc<<<BB * LL / 16, 256, 0, stream>>>(af, sel_idx, mask, fc_W, fc_b, out);
    k_mask<<<(BB * LL + 255) / 256, 256, 0, stream>>>(mask, out);
}

// Round 5
// 951.259 us; speedup vs baseline: 4.6225x; 1.3362x over previous
//
#include <hip/hip_runtime.h>
#include <math.h>

#define NAT 100000
#define MNB 12
#define FEA 64
#define NBRF 41
#define C2 128
#define HIDD 768
#define NCONV 3
#define BB 32
#define LL 512
#define EPSV 1e-5f
#define SPB 16                 // samples per block in k_conv
#define CB (NAT / SPB)         // 6250 conv blocks
#define STB 80                 // samples per block in k_st2
#define STG (NAT / STB)        // 1250 st blocks

typedef short bf16x8 __attribute__((ext_vector_type(8)));
typedef float f32x4 __attribute__((ext_vector_type(4)));

__device__ __forceinline__ float fsig(float x) {
    float e = __expf(-x);
    return __builtin_amdgcn_rcpf(1.f + e);
}
__device__ __forceinline__ float fsp(float x) {
    float e = __expf(x);
    float l = __logf(1.f + e);
    return (x > 20.f) ? x : l;
}
__device__ __forceinline__ unsigned short f2bf(float x) {
    union { float f; unsigned u; } v; v.f = x;
    unsigned r = v.u + 0x7fff + ((v.u >> 16) & 1);
    return (unsigned short)(r >> 16);
}
__device__ __forceinline__ float bf2f(unsigned short u) {
    union { unsigned u; float f; } v; v.u = ((unsigned)u) << 16; return v.f;
}

// ---------------------------------------------------------------- embed (writes f32 + bf16)
__global__ __launch_bounds__(256) void k_embed(const int* __restrict__ anum,
                                               const float* __restrict__ emb,
                                               float* __restrict__ af,
                                               unsigned short* __restrict__ af16) {
    int idx = blockIdx.x * 256 + threadIdx.x;
    if (idx >= NAT * FEA) return;
    int n = idx >> 6, c = idx & 63;
    float v = emb[anum[n] * FEA + c];
    af[idx] = v;
    af16[idx] = f2bf(v);
}

// ---------------- one-time: nbr_fea -> bf16 padded fragment layout
// Apad[sample][kbg(6)][row(16)][8]  (row>=12 or k>=41 -> 0); 1.5KB/sample
__global__ __launch_bounds__(256) void k_prepad(const float* __restrict__ nf,
                                                unsigned short* __restrict__ Apad) {
    int t = blockIdx.x * 256 + threadIdx.x;
    if (t >= NAT * 96) return;
    int row = t & 15;
    int q = t >> 4;
    int kbg = q % 6;
    int sample = q / 6;
    int k0 = kbg * 8;
    short vv[8];
    if (row < 12) {
        const float* src = nf + ((size_t)sample * MNB + row) * NBRF;
        #pragma unroll
        for (int j = 0; j < 8; ++j) {
            int k = k0 + j;
            vv[j] = (k < NBRF) ? (short)f2bf(src[k]) : (short)0;
        }
    } else {
        #pragma unroll
        for (int j = 0; j < 8; ++j) vv[j] = 0;
    }
    bf16x8 pack = {vv[0], vv[1], vv[2], vv[3], vv[4], vv[5], vv[6], vv[7]};
    *(bf16x8*)(Apad + (size_t)t * 8) = pack;
}

// ---------------- per-layer: conv B-fragments, wave-sliced channel mapping
__global__ __launch_bounds__(256) void k_wfrag(const float* __restrict__ Wb,
                                               unsigned short* __restrict__ Wfrag) {
    int idx = blockIdx.x * 256 + threadIdx.x;
    if (idx >= 8192) return;
    int j = idx & 7;
    int lane = (idx >> 3) & 63;
    int kk = (idx >> 9) & 1;
    int ct = (idx >> 10) & 1;
    int w = (idx >> 11) & 3;
    int c_loc = lane & 15, kg = lane >> 4;
    int k = kk * 32 + kg * 8 + j;
    int ch = w * 16 + c_loc + (ct ? 64 : 0);
    float v = (k < NBRF) ? Wb[(size_t)(C2 + k) * C2 + ch] : 0.f;
    Wfrag[idx] = f2bf(v);
}

// ---------------- per-layer: ST weights as A-fragments (W^T), 256 out-ch x 64 k
// idx = (((w*4+t)*2)+kk)*512 + l*8 + j ; ch_global = w*64+t*16+(l&15),
// k = kk*32+(l>>4)*8+j ; Wrow = ch<128 ? k : 64+k ; col = ch&127
__global__ __launch_bounds__(256) void k_wfrag2(const float* __restrict__ Wb,
                                                unsigned short* __restrict__ Wf2) {
    int idx = blockIdx.x * 256 + threadIdx.x;
    if (idx >= 16384) return;
    int j = idx & 7;
    int l = (idx >> 3) & 63;
    int kk = (idx >> 9) & 1;
    int t = (idx >> 10) & 3;
    int w = idx >> 12;
    int c_loc = l & 15, kg = l >> 4;
    int k = kk * 32 + kg * 8 + j;
    int chg = w * 64 + t * 16 + c_loc;
    int wrow = (chg < 128) ? k : 64 + k;
    int col = chg & 127;
    Wf2[idx] = f2bf(Wb[(size_t)wrow * C2 + col]);
}

// ---------------- S/T via MFMA: D[ch][sample] = W^T x af^T
__global__ __launch_bounds__(256) void k_st2(const unsigned short* __restrict__ af16,
                                             const unsigned short* __restrict__ Wf2,
                                             const float* __restrict__ bb,
                                             unsigned short* __restrict__ S16,
                                             unsigned short* __restrict__ T16) {
    int tid = threadIdx.x;
    int w = tid >> 6, l = tid & 63;
    int c_loc = l & 15, kg = l >> 4;
    const bf16x8* wf = (const bf16x8*)Wf2;
    bf16x8 A[8];
    #pragma unroll
    for (int t = 0; t < 4; ++t)
        #pragma unroll
        for (int kk = 0; kk < 2; ++kk)
            A[t * 2 + kk] = wf[(((w * 4 + t) * 2) + kk) * 64 + l];
    float4 bias[4];
    #pragma unroll
    for (int t = 0; t < 4; ++t)
        bias[t] = (w < 2) ? *(const float4*)&bb[w * 64 + t * 16 + kg * 4]
                          : make_float4(0.f, 0.f, 0.f, 0.f);

    size_t s0 = (size_t)blockIdx.x * STB;
    for (int st = 0; st < STB / 16; ++st) {
        size_t sbase = s0 + st * 16;
        const unsigned short* arow = af16 + (sbase + c_loc) * FEA;
        bf16x8 b0 = *(const bf16x8*)(arow + kg * 8);
        bf16x8 b1 = *(const bf16x8*)(arow + 32 + kg * 8);
        size_t n = sbase + c_loc;
        #pragma unroll
        for (int t = 0; t < 4; ++t) {
            f32x4 acc = {0.f, 0.f, 0.f, 0.f};
            acc = __builtin_amdgcn_mfma_f32_16x16x32_bf16(A[t * 2 + 0], b0, acc, 0, 0, 0);
            acc = __builtin_amdgcn_mfma_f32_16x16x32_bf16(A[t * 2 + 1], b1, acc, 0, 0, 0);
            ushort4 o;
            o.x = f2bf(acc[0] + bias[t].x);
            o.y = f2bf(acc[1] + bias[t].y);
            o.z = f2bf(acc[2] + bias[t].z);
            o.w = f2bf(acc[3] + bias[t].w);
            int chg = w * 64 + t * 16 + kg * 4;
            if (chg < 128) *(ushort4*)&S16[n * C2 + chg] = o;
            else           *(ushort4*)&T16[n * C2 + (chg - 128)] = o;
        }
    }
}

// ---------------- fused conv pass: lean-register wave-sliced version
// MODE 0: BN1 stats (128 ch). MODE 1: BN1 apply + gate + m-sum + BN2 stats (64 ch).
template<int MODE>
__global__ __launch_bounds__(256) void k_conv(const unsigned short* __restrict__ Apad,
                                              const unsigned short* __restrict__ Wfrag,
                                              const unsigned short* __restrict__ S16,
                                              const unsigned short* __restrict__ T16,
                                              const int* __restrict__ nidx,
                                              const float* __restrict__ sc1,
                                              const float* __restrict__ sh1,
                                              float* __restrict__ summed,
                                              float* __restrict__ psum,
                                              float* __restrict__ psq) {
    __shared__ __align__(16) unsigned short As[SPB * 768];   // 24KB
    __shared__ __align__(16) int NIl[SPB * 16];              // 1KB
    int tid = threadIdx.x;
    int w = tid >> 6, l = tid & 63;
    int c_loc = l & 15, kg = l >> 4;
    int blk = blockIdx.x;
    size_t s0 = (size_t)blk * SPB;

    const unsigned short* agbase = Apad + s0 * 768;
    #pragma unroll
    for (int r = 0; r < 6; ++r) {
        int t = r * 256 + tid;
        *(bf16x8*)&As[t * 8] = *(const bf16x8*)&agbase[t * 8];
    }
    {
        int s = tid >> 4, c = tid & 15;
        NIl[tid] = (c < 12) ? nidx[(s0 + s) * MNB + c] : 0;
    }

    const bf16x8* wf = (const bf16x8*)(Wfrag + (size_t)w * 2048);
    bf16x8 bF0 = wf[0 * 64 + l];
    bf16x8 bF1 = wf[1 * 64 + l];
    bf16x8 bC0 = wf[2 * 64 + l];
    bf16x8 bC1 = wf[3 * 64 + l];

    int chF = w * 16 + c_loc;
    int chC = chF + 64;
    float scF, shF, scC, shC;
    if (MODE == 1) {
        scF = sc1[chF]; shF = sh1[chF];
        scC = sc1[chC]; shC = sh1[chC];
    }

    float sA0 = 0.f, sA1 = 0.f, sB0 = 0.f, sB1 = 0.f;
    __syncthreads();

    for (int si = 0; si < SPB; ++si) {
        size_t n = s0 + si;
        bf16x8 a0 = *(const bf16x8*)&As[si * 768 + kg * 128 + c_loc * 8];
        bf16x8 a1 = {0, 0, 0, 0, 0, 0, 0, 0};
        if (kg < 2) a1 = *(const bf16x8*)&As[si * 768 + (4 + kg) * 128 + c_loc * 8];
        int4 jr = *(const int4*)&NIl[si * 16 + kg * 4];

        float Tf[4] = {0.f, 0.f, 0.f, 0.f}, Tc[4] = {0.f, 0.f, 0.f, 0.f};
        float Sf = 0.f, Sc = 0.f;
        if (kg < 3) {
            Tf[0] = bf2f(T16[(size_t)jr.x * C2 + chF]);
            Tf[1] = bf2f(T16[(size_t)jr.y * C2 + chF]);
            Tf[2] = bf2f(T16[(size_t)jr.z * C2 + chF]);
            Tf[3] = bf2f(T16[(size_t)jr.w * C2 + chF]);
            Tc[0] = bf2f(T16[(size_t)jr.x * C2 + chC]);
            Tc[1] = bf2f(T16[(size_t)jr.y * C2 + chC]);
            Tc[2] = bf2f(T16[(size_t)jr.z * C2 + chC]);
            Tc[3] = bf2f(T16[(size_t)jr.w * C2 + chC]);
            Sf = bf2f(S16[n * C2 + chF]);
            Sc = bf2f(S16[n * C2 + chC]);
        }

        f32x4 aF = {0.f, 0.f, 0.f, 0.f};
        f32x4 aC = {0.f, 0.f, 0.f, 0.f};
        aF = __builtin_amdgcn_mfma_f32_16x16x32_bf16(a0, bF0, aF, 0, 0, 0);
        aF = __builtin_amdgcn_mfma_f32_16x16x32_bf16(a1, bF1, aF, 0, 0, 0);
        aC = __builtin_amdgcn_mfma_f32_16x16x32_bf16(a0, bC0, aC, 0, 0, 0);
        aC = __builtin_amdgcn_mfma_f32_16x16x32_bf16(a1, bC1, aC, 0, 0, 0);

        if (MODE == 0) {
            if (kg < 3) {
                #pragma unroll
                for (int r = 0; r < 4; ++r) {
                    float gF = aF[r] + Sf + Tf[r];
                    float gC = aC[r] + Sc + Tc[r];
                    sA0 += gF; sB0 += gF * gF;
                    sA1 += gC; sB1 += gC * gC;
                }
            }
        } else {
            float vs = 0.f;
            if (kg < 3) {
                #pragma unroll
                for (int r = 0; r < 4; ++r) {
                    float gF = (aF[r] + Sf + Tf[r]) * scF + shF;
                    float gC = (aC[r] + Sc + Tc[r]) * scC + shC;
                    vs += fsig(gF) * fsp(gC);
                }
            }
            vs += __shfl_xor(vs, 16);
            vs += __shfl_xor(vs, 32);
            if (l < 16) summed[n * FEA + chF] = vs;
            sA0 += vs; sB0 += vs * vs;
        }
    }

    if (MODE == 0) {
        sA0 += __shfl_xor(sA0, 16); sA0 += __shfl_xor(sA0, 32);
        sB0 += __shfl_xor(sB0, 16); sB0 += __shfl_xor(sB0, 32);
        sA1 += __shfl_xor(sA1, 16); sA1 += __shfl_xor(sA1, 32);
        sB1 += __shfl_xor(sB1, 16); sB1 += __shfl_xor(sB1, 32);
        if (l < 16) {
            psum[(size_t)chF * CB + blk] = sA0;
            psq [(size_t)chF * CB + blk] = sB0;
            psum[(size_t)chC * CB + blk] = sA1;
            psq [(size_t)chC * CB + blk] = sB1;
        }
    } else {
        if (l < 16) {
            psum[(size_t)chF * CB + blk] = sA0;
            psq [(size_t)chF * CB + blk] = sB0;
        }
    }
}

// ---------------- BN finalize
__global__ __launch_bounds__(256) void k_bnfin(const float* __restrict__ psum,
                                               const float* __restrict__ psq,
                                               const float* __restrict__ g,
                                               const float* __restrict__ b,
                                               float cnt_inv,
                                               float* __restrict__ scale,
                                               float* __restrict__ shift) {
    int c = blockIdx.x;
    int tid = threadIdx.x;
    __shared__ float r1[256], r2[256];
    float s = 0.f, q = 0.f;
    for (int t = tid; t < CB; t += 256) {
        s += psum[(size_t)c * CB + t];
        q += psq[(size_t)c * CB + t];
    }
    r1[tid] = s; r2[tid] = q;
    __syncthreads();
    for (int st = 128; st > 0; st >>= 1) {
        if (tid < st) { r1[tid] += r1[tid + st]; r2[tid] += r2[tid + st]; }
        __syncthreads();
    }
    if (tid == 0) {
        float mean = r1[0] * cnt_inv;
        float var = r2[0] * cnt_inv - mean * mean;
        float sc = g[c] * rsqrtf(var + EPSV);
        scale[c] = sc;
        shift[c] = b[c] - mean * sc;
    }
}

// ---------------- residual update (float4-vectorized, also refreshes bf16 copy)
__global__ __launch_bounds__(256) void k_update(float* __restrict__ af,
                                                unsigned short* __restrict__ af16,
                                                const float* __restrict__ summed,
                                                const float* __restrict__ sc2,
                                                const float* __restrict__ sh2) {
    int t = blockIdx.x * 256 + threadIdx.x;
    if (t >= NAT * 16) return;
    float4 v = ((const float4*)af)[t];
    float4 s = ((const float4*)summed)[t];
    int c0 = (t & 15) * 4;
    v.x = fsp(v.x + s.x * sc2[c0 + 0] + sh2[c0 + 0]);
    v.y = fsp(v.y + s.y * sc2[c0 + 1] + sh2[c0 + 1]);
    v.z = fsp(v.z + s.z * sc2[c0 + 2] + sh2[c0 + 2]);
    v.w = fsp(v.w + s.w * sc2[c0 + 3] + sh2[c0 + 3]);
    ((float4*)af)[t] = v;
    ushort4 o = {f2bf(v.x), f2bf(v.y), f2bf(v.z), f2bf(v.w)};
    *(ushort4*)(af16 + (size_t)t * 4) = o;
}

// ---------------- fc on selected rows + mask
__global__ __launch_bounds__(256) void k_fc(const float* __restrict__ af,
                                            const int* __restrict__ sel,
                                            const float* __restrict__ mask,
                                            const float* __restrict__ W,
                                            const float* __restrict__ bias,
                                            float* __restrict__ out) {
    __shared__ float A[16][64];
    int tid = threadIdx.x;
    int r0 = blockIdx.x * 16;
    for (int t = tid; t < 16 * 64; t += 256) {
        int r = t >> 6, k = t & 63;
        int n = sel[r0 + r];
        A[r][k] = af[(size_t)n * FEA + k];
    }
    __syncthreads();
    float acc[16][3];
    #pragma unroll
    for (int r = 0; r < 16; ++r) { acc[r][0] = 0.f; acc[r][1] = 0.f; acc[r][2] = 0.f; }
    for (int k = 0; k < 64; ++k) {
        float w0 = W[(size_t)k * HIDD + tid];
        float w1 = W[(size_t)k * HIDD + 256 + tid];
        float w2 = W[(size_t)k * HIDD + 512 + tid];
        #pragma unroll
        for (int r = 0; r < 16; ++r) {
            float a = A[r][k];
            acc[r][0] = fmaf(a, w0, acc[r][0]);
            acc[r][1] = fmaf(a, w1, acc[r][1]);
            acc[r][2] = fmaf(a, w2, acc[r][2]);
        }
    }
    float b0 = bias[tid], b1 = bias[256 + tid], b2 = bias[512 + tid];
    #pragma unroll
    for (int r = 0; r < 16; ++r) {
        float mv = mask[r0 + r];
        size_t base = (size_t)(r0 + r) * HIDD;
        out[base + tid] = (acc[r][0] + b0) * mv;
        out[base + 256 + tid] = (acc[r][1] + b1) * mv;
        out[base + 512 + tid] = (acc[r][2] + b2) * mv;
    }
}

__global__ __launch_bounds__(256) void k_mask(const float* __restrict__ mask,
                                              float* __restrict__ out) {
    int idx = blockIdx.x * 256 + threadIdx.x;
    if (idx < BB * LL) out[(size_t)BB * LL * HIDD + idx] = mask[idx];
}

// ---------------------------------------------------------------- launch
extern "C" void kernel_launch(void* const* d_in, const int* in_sizes, int n_in,
                              void* d_out, int out_size, void* d_ws, size_t ws_size,
                              hipStream_t stream) {
    const int* atom_num  = (const int*)d_in[0];
    const int* nbr_idx   = (const int*)d_in[1];
    const float* nbr_fea = (const float*)d_in[2];
    const int* sel_idx   = (const int*)d_in[3];
    const float* mask    = (const float*)d_in[4];
    const float* emb     = (const float*)d_in[5];
    const float* conv_W  = (const float*)d_in[6];
    const float* conv_b  = (const float*)d_in[7];
    const float* bn1_g   = (const float*)d_in[8];
    const float* bn1_b   = (const float*)d_in[9];
    const float* bn2_g   = (const float*)d_in[10];
    const float* bn2_b   = (const float*)d_in[11];
    const float* fc_W    = (const float*)d_in[12];
    const float* fc_b    = (const float*)d_in[13];
    float* out = (float*)d_out;

    char* p = (char*)d_ws;
    float* af = (float*)p;                      p += (size_t)NAT * FEA * 4;
    unsigned short* af16 = (unsigned short*)p;  p += (size_t)NAT * FEA * 2;
    unsigned short* S16 = (unsigned short*)p;   p += (size_t)NAT * C2 * 2;
    unsigned short* T16 = (unsigned short*)p;   p += (size_t)NAT * C2 * 2;
    float* summed = (float*)p;                  p += (size_t)NAT * FEA * 4;
    float* psum = (float*)p;                    p += (size_t)C2 * CB * 4;
    float* psq = (float*)p;                     p += (size_t)C2 * CB * 4;
    float* sc1 = (float*)p;                     p += 512;
    float* sh1 = (float*)p;                     p += 512;
    float* sc2 = (float*)p;                     p += 512;
    float* sh2 = (float*)p;                     p += 512;
    unsigned short* Wfrag = (unsigned short*)p; p += 16384;
    unsigned short* Wf2 = (unsigned short*)p;   p += 32768;
    unsigned short* Apad = (unsigned short*)p;  p += (size_t)NAT * 768 * 2;

    k_embed<<<(NAT * FEA) / 256, 256, 0, stream>>>(atom_num, emb, af, af16);
    k_prepad<<<(NAT * 96) / 256, 256, 0, stream>>>(nbr_fea, Apad);

    for (int i = 0; i < NCONV; ++i) {
        const float* Wb = conv_W + (size_t)i * 169 * C2;
        k_wfrag<<<32, 256, 0, stream>>>(Wb, Wfrag);
        k_wfrag2<<<64, 256, 0, stream>>>(Wb, Wf2);
        k_st2<<<STG, 256, 0, stream>>>(af16, Wf2, conv_b + i * C2, S16, T16);
        k_conv<0><<<CB, 256, 0, stream>>>(Apad, Wfrag, S16, T16, nbr_idx,
                                          sc1, sh1, summed, psum, psq);
        k_bnfin<<<C2, 256, 0, stream>>>(psum, psq, bn1_g + i * C2, bn1_b + i * C2,
                                        1.f / (float)(NAT * (long)MNB), sc1, sh1);
        k_conv<1><<<CB, 256, 0, stream>>>(Apad, Wfrag, S16, T16, nbr_idx,
                                          sc1, sh1, summed, psum, psq);
        k_bnfin<<<FEA, 256, 0, stream>>>(psum, psq, bn2_g + i * FEA, bn2_b + i * FEA,
                                         1.f / (float)NAT, sc2, sh2);
        k_update<<<(NAT * 16) / 256, 256, 0, stream>>>(af, af16, summed, sc2, sh2);
    }

    k_fc<<<BB * LL / 16, 256, 0, stream>>>(af, sel_idx, mask, fc_W, fc_b, out);
    k_mask<<<(BB * LL + 255) / 256, 256, 0, stream>>>(mask, out);
}

// Round 7
// 947.230 us; speedup vs baseline: 4.6422x; 1.0043x over previous
//
#include <hip/hip_runtime.h>
#include <math.h>

#define NAT 100000
#define MNB 12
#define FEA 64
#define NBRF 41
#define C2 128
#define HIDD 768
#define NCONV 3
#define BB 32
#define LL 512
#define EPSV 1e-5f
#define SPB 16                 // samples per block in k_conv
#define CB (NAT / SPB)         // 6250 conv blocks
#define STB 80                 // samples per block in k_st2
#define STG (NAT / STB)        // 1250 st blocks
#define ASTRIDE 576            // ushorts per sample in Apad (6 kbg x 12 rows x 8)
#define APAD_SAMP (NAT + 2)    // 2 zeroed guard samples for a1 over-read

typedef short bf16x8 __attribute__((ext_vector_type(8)));
typedef float f32x4 __attribute__((ext_vector_type(4)));

__device__ __forceinline__ float fsig(float x) {
    float e = __expf(-x);
    return __builtin_amdgcn_rcpf(1.f + e);
}
__device__ __forceinline__ float fsp(float x) {
    float e = __expf(x);
    float l = __logf(1.f + e);
    return (x > 20.f) ? x : l;
}
__device__ __forceinline__ unsigned short f2bf(float x) {
    union { float f; unsigned u; } v; v.f = x;
    unsigned r = v.u + 0x7fff + ((v.u >> 16) & 1);
    return (unsigned short)(r >> 16);
}
__device__ __forceinline__ float bf2f(unsigned short u) {
    union { unsigned u; float f; } v; v.u = ((unsigned)u) << 16; return v.f;
}
__device__ __forceinline__ float lo_bf(unsigned int u) {
    union { unsigned u; float f; } v; v.u = u << 16; return v.f;
}
__device__ __forceinline__ float hi_bf(unsigned int u) {
    union { unsigned u; float f; } v; v.u = u & 0xFFFF0000u; return v.f;
}

// ---------------------------------------------------------------- embed (f32 + bf16)
__global__ __launch_bounds__(256) void k_embed(const int* __restrict__ anum,
                                               const float* __restrict__ emb,
                                               float* __restrict__ af,
                                               unsigned short* __restrict__ af16) {
    int idx = blockIdx.x * 256 + threadIdx.x;
    if (idx >= NAT * FEA) return;
    int n = idx >> 6, c = idx & 63;
    float v = emb[anum[n] * FEA + c];
    af[idx] = v;
    af16[idx] = f2bf(v);
}

// ---------------- one-time: nbr_fea -> bf16 fragment layout (12 rows), +2 zero samples
// Apad[sample][kbg(6)][row(12)][8]; k>=41 -> 0; sample>=NAT -> all zero
__global__ __launch_bounds__(256) void k_prepad(const float* __restrict__ nf,
                                                unsigned short* __restrict__ Apad) {
    int t = blockIdx.x * 256 + threadIdx.x;   // 0 .. APAD_SAMP*72-1
    if (t >= APAD_SAMP * 72) return;
    int row = t % 12;
    int q = t / 12;
    int kbg = q % 6;
    int sample = q / 6;
    int k0 = kbg * 8;
    short vv[8];
    if (sample < NAT) {
        const float* src = nf + ((size_t)sample * MNB + row) * NBRF;
        #pragma unroll
        for (int j = 0; j < 8; ++j) {
            int k = k0 + j;
            vv[j] = (k < NBRF) ? (short)f2bf(src[k]) : (short)0;
        }
    } else {
        #pragma unroll
        for (int j = 0; j < 8; ++j) vv[j] = 0;
    }
    bf16x8 pack = {vv[0], vv[1], vv[2], vv[3], vv[4], vv[5], vv[6], vv[7]};
    *(bf16x8*)(Apad + (size_t)t * 8) = pack;
}

// ---------------- per-layer: conv B-fragments (unchanged mapping)
__global__ __launch_bounds__(256) void k_wfrag(const float* __restrict__ Wb,
                                               unsigned short* __restrict__ Wfrag) {
    int idx = blockIdx.x * 256 + threadIdx.x;
    if (idx >= 8192) return;
    int j = idx & 7;
    int lane = (idx >> 3) & 63;
    int kk = (idx >> 9) & 1;
    int ct = (idx >> 10) & 1;
    int w = (idx >> 11) & 3;
    int c_loc = lane & 15, kg = lane >> 4;
    int k = kk * 32 + kg * 8 + j;
    int ch = w * 16 + c_loc + (ct ? 64 : 0);
    float v = (k < NBRF) ? Wb[(size_t)(C2 + k) * C2 + ch] : 0.f;
    Wfrag[idx] = f2bf(v);
}

// ---------------- per-layer: ST weights as A-fragments, PAIRED row->channel map
// D-row ar of (w,t): h=(ar>>1)&1, e=ar&1, P = w*32 + t*8 + (ar>>2)*2 + h
// P<64 -> S pair P (ch = P + e*64, wrow = k); else T pair P-64 (ch=(P-64)+e*64, wrow=64+k)
__global__ __launch_bounds__(256) void k_wfrag2(const float* __restrict__ Wb,
                                                unsigned short* __restrict__ Wf2) {
    int idx = blockIdx.x * 256 + threadIdx.x;
    if (idx >= 16384) return;
    int j = idx & 7;
    int l = (idx >> 3) & 63;
    int kk = (idx >> 9) & 1;
    int t = (idx >> 10) & 3;
    int w = idx >> 12;
    int ar = l & 15, kgf = l >> 4;
    int k = kk * 32 + kgf * 8 + j;
    int h = (ar >> 1) & 1, e = ar & 1;
    int P = w * 32 + t * 8 + (ar >> 2) * 2 + h;
    int ch, wrow;
    if (P < 64) { ch = P + e * 64; wrow = k; }
    else        { ch = (P - 64) + e * 64; wrow = 64 + k; }
    Wf2[idx] = f2bf(Wb[(size_t)wrow * C2 + ch]);
}

// ---------------- S/T via MFMA, writing PAIRED layout (uint2 stores)
__global__ __launch_bounds__(256) void k_st2(const unsigned short* __restrict__ af16,
                                             const unsigned short* __restrict__ Wf2,
                                             const float* __restrict__ bb,
                                             unsigned short* __restrict__ S16p,
                                             unsigned short* __restrict__ T16p) {
    int tid = threadIdx.x;
    int w = tid >> 6, l = tid & 63;
    int c_loc = l & 15, kg = l >> 4;
    const bf16x8* wf = (const bf16x8*)Wf2;
    bf16x8 A[8];
    #pragma unroll
    for (int t = 0; t < 4; ++t)
        #pragma unroll
        for (int kk = 0; kk < 2; ++kk)
            A[t * 2 + kk] = wf[(((w * 4 + t) * 2) + kk) * 64 + l];

    bool sside = (w < 2);
    float bv[4][4];
    int P0t[4];
    #pragma unroll
    for (int t = 0; t < 4; ++t) {
        int P0 = w * 32 + t * 8 + kg * 2;
        P0t[t] = P0;
        bv[t][0] = sside ? bb[P0] : 0.f;
        bv[t][1] = sside ? bb[P0 + 64] : 0.f;
        bv[t][2] = sside ? bb[P0 + 1] : 0.f;
        bv[t][3] = sside ? bb[P0 + 65] : 0.f;
    }
    unsigned int* dst0 = (unsigned int*)(sside ? S16p : T16p);
    int poff = sside ? 0 : 64;

    size_t s0 = (size_t)blockIdx.x * STB;
    for (int st = 0; st < STB / 16; ++st) {
        size_t sbase = s0 + st * 16;
        const unsigned short* arow = af16 + (sbase + c_loc) * FEA;
        bf16x8 b0 = *(const bf16x8*)(arow + kg * 8);
        bf16x8 b1 = *(const bf16x8*)(arow + 32 + kg * 8);
        size_t n = sbase + c_loc;
        unsigned int* dstn = dst0 + n * 64;
        #pragma unroll
        for (int t = 0; t < 4; ++t) {
            f32x4 acc = {0.f, 0.f, 0.f, 0.f};
            acc = __builtin_amdgcn_mfma_f32_16x16x32_bf16(A[t * 2 + 0], b0, acc, 0, 0, 0);
            acc = __builtin_amdgcn_mfma_f32_16x16x32_bf16(A[t * 2 + 1], b1, acc, 0, 0, 0);
            unsigned int u0 = (unsigned int)f2bf(acc[0] + bv[t][0]) |
                              ((unsigned int)f2bf(acc[1] + bv[t][1]) << 16);
            unsigned int u1 = (unsigned int)f2bf(acc[2] + bv[t][2]) |
                              ((unsigned int)f2bf(acc[3] + bv[t][3]) << 16);
            uint2 u01 = {u0, u1};
            *(uint2*)&dstn[P0t[t] - poff] = u01;
        }
    }
}

// ---------------- fused conv pass: LDS-free, dword-paired gathers
// MODE 0: BN1 stats (128 ch). MODE 1: BN1 apply + gate + m-sum + BN2 stats (64 ch).
template<int MODE>
__global__ __launch_bounds__(256) void k_conv(const unsigned short* __restrict__ Apad,
                                              const unsigned short* __restrict__ Wfrag,
                                              const unsigned short* __restrict__ S16p,
                                              const unsigned short* __restrict__ T16p,
                                              const int* __restrict__ nidx,
                                              const float* __restrict__ sc1,
                                              const float* __restrict__ sh1,
                                              float* __restrict__ summed,
                                              float* __restrict__ psum,
                                              float* __restrict__ psq) {
    int tid = threadIdx.x;
    int w = tid >> 6, l = tid & 63;
    int c_loc = l & 15, kg = l >> 4;
    int blk = blockIdx.x;
    size_t s0 = (size_t)blk * SPB;

    const bf16x8* wf = (const bf16x8*)(Wfrag + (size_t)w * 2048);
    bf16x8 bF0 = wf[0 * 64 + l];
    bf16x8 bF1 = wf[1 * 64 + l];
    bf16x8 bC0 = wf[2 * 64 + l];
    bf16x8 bC1 = wf[3 * 64 + l];

    int chF = w * 16 + c_loc;
    int m_off = (kg < 3) ? kg * 4 : 8;

    const unsigned short* aptr = Apad + s0 * ASTRIDE + kg * 96 + c_loc * 8;
    const int* np = nidx + s0 * 12 + m_off;
    const unsigned int* sp = (const unsigned int*)S16p + s0 * 64 + chF;
    const unsigned int* Tb = (const unsigned int*)T16p + chF;

    float scF, shF, scC, shC;
    if (MODE == 1) {
        scF = sc1[chF]; shF = sh1[chF];
        scC = sc1[chF + 64]; shC = sh1[chF + 64];
    }

    float sA0 = 0.f, sB0 = 0.f, sA1 = 0.f, sB1 = 0.f;

    for (int si = 0; si < SPB; ++si) {
        bf16x8 a0 = *(const bf16x8*)aptr;
        bf16x8 a1 = *(const bf16x8*)(aptr + 384);   // kbg 4..5 (k 32..47); kg>=2 reads
                                                    // zero-padded guard / next-sample
                                                    // data annihilated by W=0 columns
        int4 jr = *(const int4*)np;
        unsigned int sdw = *sp;
        unsigned int td0 = Tb[(unsigned int)jr.x << 6];
        unsigned int td1 = Tb[(unsigned int)jr.y << 6];
        unsigned int td2 = Tb[(unsigned int)jr.z << 6];
        unsigned int td3 = Tb[(unsigned int)jr.w << 6];

        f32x4 aF = {0.f, 0.f, 0.f, 0.f};
        f32x4 aC = {0.f, 0.f, 0.f, 0.f};
        aF = __builtin_amdgcn_mfma_f32_16x16x32_bf16(a0, bF0, aF, 0, 0, 0);
        aF = __builtin_amdgcn_mfma_f32_16x16x32_bf16(a1, bF1, aF, 0, 0, 0);
        aC = __builtin_amdgcn_mfma_f32_16x16x32_bf16(a0, bC0, aC, 0, 0, 0);
        aC = __builtin_amdgcn_mfma_f32_16x16x32_bf16(a1, bC1, aC, 0, 0, 0);

        float Sf = lo_bf(sdw), Sc = hi_bf(sdw);

        if (MODE == 0) {
            if (kg < 3) {
                float gF, gC;
                gF = aF[0] + Sf + lo_bf(td0); gC = aC[0] + Sc + hi_bf(td0);
                sA0 += gF; sB0 += gF * gF; sA1 += gC; sB1 += gC * gC;
                gF = aF[1] + Sf + lo_bf(td1); gC = aC[1] + Sc + hi_bf(td1);
                sA0 += gF; sB0 += gF * gF; sA1 += gC; sB1 += gC * gC;
                gF = aF[2] + Sf + lo_bf(td2); gC = aC[2] + Sc + hi_bf(td2);
                sA0 += gF; sB0 += gF * gF; sA1 += gC; sB1 += gC * gC;
                gF = aF[3] + Sf + lo_bf(td3); gC = aC[3] + Sc + hi_bf(td3);
                sA0 += gF; sB0 += gF * gF; sA1 += gC; sB1 += gC * gC;
            }
        } else {
            float vs = 0.f;
            if (kg < 3) {
                float gF, gC;
                gF = (aF[0] + Sf + lo_bf(td0)) * scF + shF;
                gC = (aC[0] + Sc + hi_bf(td0)) * scC + shC;
                vs += fsig(gF) * fsp(gC);
                gF = (aF[1] + Sf + lo_bf(td1)) * scF + shF;
                gC = (aC[1] + Sc + hi_bf(td1)) * scC + shC;
                vs += fsig(gF) * fsp(gC);
                gF = (aF[2] + Sf + lo_bf(td2)) * scF + shF;
                gC = (aC[2] + Sc + hi_bf(td2)) * scC + shC;
                vs += fsig(gF) * fsp(gC);
                gF = (aF[3] + Sf + lo_bf(td3)) * scF + shF;
                gC = (aC[3] + Sc + hi_bf(td3)) * scC + shC;
                vs += fsig(gF) * fsp(gC);
            }
            vs += __shfl_xor(vs, 16);
            vs += __shfl_xor(vs, 32);
            if (l < 16) summed[(s0 + si) * FEA + chF] = vs;
            sA0 += vs; sB0 += vs * vs;
        }
        aptr += ASTRIDE; np += 12; sp += 64;
    }

    if (MODE == 0) {
        sA0 += __shfl_xor(sA0, 16); sA0 += __shfl_xor(sA0, 32);
        sB0 += __shfl_xor(sB0, 16); sB0 += __shfl_xor(sB0, 32);
        sA1 += __shfl_xor(sA1, 16); sA1 += __shfl_xor(sA1, 32);
        sB1 += __shfl_xor(sB1, 16); sB1 += __shfl_xor(sB1, 32);
        if (l < 16) {
            psum[(size_t)chF * CB + blk] = sA0;
            psq [(size_t)chF * CB + blk] = sB0;
            psum[(size_t)(chF + 64) * CB + blk] = sA1;
            psq [(size_t)(chF + 64) * CB + blk] = sB1;
        }
    } else {
        if (l < 16) {
            psum[(size_t)chF * CB + blk] = sA0;
            psq [(size_t)chF * CB + blk] = sB0;
        }
    }
}

// ---------------- BN finalize
__global__ __launch_bounds__(256) void k_bnfin(const float* __restrict__ psum,
                                               const float* __restrict__ psq,
                                               const float* __restrict__ g,
                                               const float* __restrict__ b,
                                               float cnt_inv,
                                               float* __restrict__ scale,
                                               float* __restrict__ shift) {
    int c = blockIdx.x;
    int tid = threadIdx.x;
    __shared__ float r1[256], r2[256];
    float s = 0.f, q = 0.f;
    for (int t = tid; t < CB; t += 256) {
        s += psum[(size_t)c * CB + t];
        q += psq[(size_t)c * CB + t];
    }
    r1[tid] = s; r2[tid] = q;
    __syncthreads();
    for (int st = 128; st > 0; st >>= 1) {
        if (tid < st) { r1[tid] += r1[tid + st]; r2[tid] += r2[tid + st]; }
        __syncthreads();
    }
    if (tid == 0) {
        float mean = r1[0] * cnt_inv;
        float var = r2[0] * cnt_inv - mean * mean;
        float sc = g[c] * rsqrtf(var + EPSV);
        scale[c] = sc;
        shift[c] = b[c] - mean * sc;
    }
}

// ---------------- residual update (float4, refreshes bf16 copy)
__global__ __launch_bounds__(256) void k_update(float* __restrict__ af,
                                                unsigned short* __restrict__ af16,
                                                const float* __restrict__ summed,
                                                const float* __restrict__ sc2,
                                                const float* __restrict__ sh2) {
    int t = blockIdx.x * 256 + threadIdx.x;
    if (t >= NAT * 16) return;
    float4 v = ((const float4*)af)[t];
    float4 s = ((const float4*)summed)[t];
    int c0 = (t & 15) * 4;
    v.x = fsp(v.x + s.x * sc2[c0 + 0] + sh2[c0 + 0]);
    v.y = fsp(v.y + s.y * sc2[c0 + 1] + sh2[c0 + 1]);
    v.z = fsp(v.z + s.z * sc2[c0 + 2] + sh2[c0 + 2]);
    v.w = fsp(v.w + s.w * sc2[c0 + 3] + sh2[c0 + 3]);
    ((float4*)af)[t] = v;
    ushort4 o = {f2bf(v.x), f2bf(v.y), f2bf(v.z), f2bf(v.w)};
    *(ushort4*)(af16 + (size_t)t * 4) = o;
}

// ---------------- fc on selected rows + mask
__global__ __launch_bounds__(256) void k_fc(const float* __restrict__ af,
                                            const int* __restrict__ sel,
                                            const float* __restrict__ mask,
                                            const float* __restrict__ W,
                                            const float* __restrict__ bias,
                                            float* __restrict__ out) {
    __shared__ float A[16][64];
    int tid = threadIdx.x;
    int r0 = blockIdx.x * 16;
    for (int t = tid; t < 16 * 64; t += 256) {
        int r = t >> 6, k = t & 63;
        int n = sel[r0 + r];
        A[r][k] = af[(size_t)n * FEA + k];
    }
    __syncthreads();
    float acc[16][3];
    #pragma unroll
    for (int r = 0; r < 16; ++r) { acc[r][0] = 0.f; acc[r][1] = 0.f; acc[r][2] = 0.f; }
    for (int k = 0; k < 64; ++k) {
        float w0 = W[(size_t)k * HIDD + tid];
        float w1 = W[(size_t)k * HIDD + 256 + tid];
        float w2 = W[(size_t)k * HIDD + 512 + tid];
        #pragma unroll
        for (int r = 0; r < 16; ++r) {
            float a = A[r][k];
            acc[r][0] = fmaf(a, w0, acc[r][0]);
            acc[r][1] = fmaf(a, w1, acc[r][1]);
            acc[r][2] = fmaf(a, w2, acc[r][2]);
        }
    }
    float b0 = bias[tid], b1 = bias[256 + tid], b2 = bias[512 + tid];
    #pragma unroll
    for (int r = 0; r < 16; ++r) {
        float mv = mask[r0 + r];
        size_t base = (size_t)(r0 + r) * HIDD;
        out[base + tid] = (acc[r][0] + b0) * mv;
        out[base + 256 + tid] = (acc[r][1] + b1) * mv;
        out[base + 512 + tid] = (acc[r][2] + b2) * mv;
    }
}

__global__ __launch_bounds__(256) void k_mask(const float* __restrict__ mask,
                                              float* __restrict__ out) {
    int idx = blockIdx.x * 256 + threadIdx.x;
    if (idx < BB * LL) out[(size_t)BB * LL * HIDD + idx] = mask[idx];
}

// ---------------------------------------------------------------- launch
extern "C" void kernel_launch(void* const* d_in, const int* in_sizes, int n_in,
                              void* d_out, int out_size, void* d_ws, size_t ws_size,
                              hipStream_t stream) {
    const int* atom_num  = (const int*)d_in[0];
    const int* nbr_idx   = (const int*)d_in[1];
    const float* nbr_fea = (const float*)d_in[2];
    const int* sel_idx   = (const int*)d_in[3];
    const float* mask    = (const float*)d_in[4];
    const float* emb     = (const float*)d_in[5];
    const float* conv_W  = (const float*)d_in[6];
    const float* conv_b  = (const float*)d_in[7];
    const float* bn1_g   = (const float*)d_in[8];
    const float* bn1_b   = (const float*)d_in[9];
    const float* bn2_g   = (const float*)d_in[10];
    const float* bn2_b   = (const float*)d_in[11];
    const float* fc_W    = (const float*)d_in[12];
    const float* fc_b    = (const float*)d_in[13];
    float* out = (float*)d_out;

    char* p = (char*)d_ws;
    float* af = (float*)p;                      p += (size_t)NAT * FEA * 4;
    unsigned short* af16 = (unsigned short*)p;  p += (size_t)NAT * FEA * 2;
    unsigned short* S16p = (unsigned short*)p;  p += (size_t)NAT * C2 * 2;
    unsigned short* T16p = (unsigned short*)p;  p += (size_t)NAT * C2 * 2;
    float* summed = (float*)p;                  p += (size_t)NAT * FEA * 4;
    float* sc1 = (float*)p;                     p += 512;
    float* sh1 = (float*)p;                     p += 512;
    float* sc2 = (float*)p;                     p += 512;
    float* sh2 = (float*)p;                     p += 512;
    unsigned short* Wfrag = (unsigned short*)p; p += 16384;
    unsigned short* Wf2 = (unsigned short*)p;   p += 32768;
    unsigned short* Apad = (unsigned short*)p;  p += (size_t)APAD_SAMP * ASTRIDE * 2;
    float* psum = (float*)p;                    p += (size_t)C2 * CB * 4;
    float* psq = (float*)p;                     p += (size_t)C2 * CB * 4;

    k_embed<<<(NAT * FEA) / 256, 256, 0, stream>>>(atom_num, emb, af, af16);
    k_prepad<<<(APAD_SAMP * 72 + 255) / 256, 256, 0, stream>>>(nbr_fea, Apad);

    for (int i = 0; i < NCONV; ++i) {
        const float* Wb = conv_W + (size_t)i * 169 * C2;
        k_wfrag<<<32, 256, 0, stream>>>(Wb, Wfrag);
        k_wfrag2<<<64, 256, 0, stream>>>(Wb, Wf2);
        k_st2<<<STG, 256, 0, stream>>>(af16, Wf2, conv_b + i * C2, S16p, T16p);
        k_conv<0><<<CB, 256, 0, stream>>>(Apad, Wfrag, S16p, T16p, nbr_idx,
                                          sc1, sh1, summed, psum, psq);
        k_bnfin<<<C2, 256, 0, stream>>>(psum, psq, bn1_g + i * C2, bn1_b + i * C2,
                                        1.f / (float)(NAT * (long)MNB), sc1, sh1);
        k_conv<1><<<CB, 256, 0, stream>>>(Apad, Wfrag, S16p, T16p, nbr_idx,
                                          sc1, sh1, summed, psum, psq);
        k_bnfin<<<FEA, 256, 0, stream>>>(psum, psq, bn2_g + i * FEA, bn2_b + i * FEA,
                                         1.f / (float)NAT, sc2, sh2);
        k_update<<<(NAT * 16) / 256, 256, 0, stream>>>(af, af16, summed, sc2, sh2);
    }

    k_fc<<<BB * LL / 16, 256, 0, stream>>>(af, sel_idx, mask, fc_W, fc_b, out);
    k_mask<<<(BB * LL + 255) / 256, 256, 0, stream>>>(mask, out);
}

// Round 8
// 898.947 us; speedup vs baseline: 4.8915x; 1.0537x over previous
//
#include <hip/hip_runtime.h>
#include <math.h>

#define NAT 100000
#define MNB 12
#define FEA 64
#define NBRF 41
#define C2 128
#define HIDD 768
#define NCONV 3
#define BB 32
#define LL 512
#define EPSV 1e-5f
#define SPB 16                 // samples per block in k_conv
#define CB (NAT / SPB)         // 6250 conv blocks
#define STB 80                 // samples per block in k_st2
#define STG (NAT / STB)        // 1250 st blocks
#define ASTRIDE 576            // ushorts per sample in Apad (6 kbg x 12 rows x 8)
#define APAD_SAMP (NAT + 4)    // zeroed guard samples for prefetch/a1 over-read

typedef short bf16x8 __attribute__((ext_vector_type(8)));
typedef float f32x4 __attribute__((ext_vector_type(4)));

__device__ __forceinline__ float fsig(float x) {
    float e = __expf(-x);
    return __builtin_amdgcn_rcpf(1.f + e);
}
__device__ __forceinline__ float fsp(float x) {
    float e = __expf(x);
    float l = __logf(1.f + e);
    return (x > 20.f) ? x : l;
}
__device__ __forceinline__ unsigned short f2bf(float x) {
    union { float f; unsigned u; } v; v.f = x;
    unsigned r = v.u + 0x7fff + ((v.u >> 16) & 1);
    return (unsigned short)(r >> 16);
}
__device__ __forceinline__ float bf2f(unsigned short u) {
    union { unsigned u; float f; } v; v.u = ((unsigned)u) << 16; return v.f;
}
__device__ __forceinline__ float lo_bf(unsigned int u) {
    union { unsigned u; float f; } v; v.u = u << 16; return v.f;
}
__device__ __forceinline__ float hi_bf(unsigned int u) {
    union { unsigned u; float f; } v; v.u = u & 0xFFFF0000u; return v.f;
}

// ---------------------------------------------------------------- embed (f32 + bf16)
__global__ __launch_bounds__(256) void k_embed(const int* __restrict__ anum,
                                               const float* __restrict__ emb,
                                               float* __restrict__ af,
                                               unsigned short* __restrict__ af16) {
    int idx = blockIdx.x * 256 + threadIdx.x;
    if (idx >= NAT * FEA) return;
    int n = idx >> 6, c = idx & 63;
    float v = emb[anum[n] * FEA + c];
    af[idx] = v;
    af16[idx] = f2bf(v);
}

// ---------------- one-time: nbr_fea -> bf16 fragment layout (12 rows), + zero guards
__global__ __launch_bounds__(256) void k_prepad(const float* __restrict__ nf,
                                                unsigned short* __restrict__ Apad) {
    int t = blockIdx.x * 256 + threadIdx.x;   // 0 .. APAD_SAMP*72-1
    if (t >= APAD_SAMP * 72) return;
    int row = t % 12;
    int q = t / 12;
    int kbg = q % 6;
    int sample = q / 6;
    int k0 = kbg * 8;
    short vv[8];
    if (sample < NAT) {
        const float* src = nf + ((size_t)sample * MNB + row) * NBRF;
        #pragma unroll
        for (int j = 0; j < 8; ++j) {
            int k = k0 + j;
            vv[j] = (k < NBRF) ? (short)f2bf(src[k]) : (short)0;
        }
    } else {
        #pragma unroll
        for (int j = 0; j < 8; ++j) vv[j] = 0;
    }
    bf16x8 pack = {vv[0], vv[1], vv[2], vv[3], vv[4], vv[5], vv[6], vv[7]};
    *(bf16x8*)(Apad + (size_t)t * 8) = pack;
}

// ---------------- per-layer: conv B-fragments (unchanged mapping)
__global__ __launch_bounds__(256) void k_wfrag(const float* __restrict__ Wb,
                                               unsigned short* __restrict__ Wfrag) {
    int idx = blockIdx.x * 256 + threadIdx.x;
    if (idx >= 8192) return;
    int j = idx & 7;
    int lane = (idx >> 3) & 63;
    int kk = (idx >> 9) & 1;
    int ct = (idx >> 10) & 1;
    int w = (idx >> 11) & 3;
    int c_loc = lane & 15, kg = lane >> 4;
    int k = kk * 32 + kg * 8 + j;
    int ch = w * 16 + c_loc + (ct ? 64 : 0);
    float v = (k < NBRF) ? Wb[(size_t)(C2 + k) * C2 + ch] : 0.f;
    Wfrag[idx] = f2bf(v);
}

// ---------------- per-layer: ST weights as A-fragments, PAIRED row->channel map
__global__ __launch_bounds__(256) void k_wfrag2(const float* __restrict__ Wb,
                                                unsigned short* __restrict__ Wf2) {
    int idx = blockIdx.x * 256 + threadIdx.x;
    if (idx >= 16384) return;
    int j = idx & 7;
    int l = (idx >> 3) & 63;
    int kk = (idx >> 9) & 1;
    int t = (idx >> 10) & 3;
    int w = idx >> 12;
    int ar = l & 15, kgf = l >> 4;
    int k = kk * 32 + kgf * 8 + j;
    int h = (ar >> 1) & 1, e = ar & 1;
    int P = w * 32 + t * 8 + (ar >> 2) * 2 + h;
    int ch, wrow;
    if (P < 64) { ch = P + e * 64; wrow = k; }
    else        { ch = (P - 64) + e * 64; wrow = 64 + k; }
    Wf2[idx] = f2bf(Wb[(size_t)wrow * C2 + ch]);
}

// ---------------- S/T via MFMA, writing PAIRED layout (uint2 stores)
__global__ __launch_bounds__(256) void k_st2(const unsigned short* __restrict__ af16,
                                             const unsigned short* __restrict__ Wf2,
                                             const float* __restrict__ bb,
                                             unsigned short* __restrict__ S16p,
                                             unsigned short* __restrict__ T16p) {
    int tid = threadIdx.x;
    int w = tid >> 6, l = tid & 63;
    int c_loc = l & 15, kg = l >> 4;
    const bf16x8* wf = (const bf16x8*)Wf2;
    bf16x8 A[8];
    #pragma unroll
    for (int t = 0; t < 4; ++t)
        #pragma unroll
        for (int kk = 0; kk < 2; ++kk)
            A[t * 2 + kk] = wf[(((w * 4 + t) * 2) + kk) * 64 + l];

    bool sside = (w < 2);
    float bv[4][4];
    int P0t[4];
    #pragma unroll
    for (int t = 0; t < 4; ++t) {
        int P0 = w * 32 + t * 8 + kg * 2;
        P0t[t] = P0;
        bv[t][0] = sside ? bb[P0] : 0.f;
        bv[t][1] = sside ? bb[P0 + 64] : 0.f;
        bv[t][2] = sside ? bb[P0 + 1] : 0.f;
        bv[t][3] = sside ? bb[P0 + 65] : 0.f;
    }
    unsigned int* dst0 = (unsigned int*)(sside ? S16p : T16p);
    int poff = sside ? 0 : 64;

    size_t s0 = (size_t)blockIdx.x * STB;
    for (int st = 0; st < STB / 16; ++st) {
        size_t sbase = s0 + st * 16;
        const unsigned short* arow = af16 + (sbase + c_loc) * FEA;
        bf16x8 b0 = *(const bf16x8*)(arow + kg * 8);
        bf16x8 b1 = *(const bf16x8*)(arow + 32 + kg * 8);
        size_t n = sbase + c_loc;
        unsigned int* dstn = dst0 + n * 64;
        #pragma unroll
        for (int t = 0; t < 4; ++t) {
            f32x4 acc = {0.f, 0.f, 0.f, 0.f};
            acc = __builtin_amdgcn_mfma_f32_16x16x32_bf16(A[t * 2 + 0], b0, acc, 0, 0, 0);
            acc = __builtin_amdgcn_mfma_f32_16x16x32_bf16(A[t * 2 + 1], b1, acc, 0, 0, 0);
            unsigned int u0 = (unsigned int)f2bf(acc[0] + bv[t][0]) |
                              ((unsigned int)f2bf(acc[1] + bv[t][1]) << 16);
            unsigned int u1 = (unsigned int)f2bf(acc[2] + bv[t][2]) |
                              ((unsigned int)f2bf(acc[3] + bv[t][3]) << 16);
            uint2 u01 = {u0, u1};
            *(uint2*)&dstn[P0t[t] - poff] = u01;
        }
    }
}

// ---------------- fused conv pass v3: 2-deep software pipeline, S+T folded into acc
// MODE 0: BN1 stats (128 ch). MODE 1: BN1 apply + gate + m-sum + BN2 stats (64 ch).
template<int MODE>
__global__ __launch_bounds__(256) void k_conv(const unsigned short* __restrict__ Apad,
                                              const unsigned short* __restrict__ Wfrag,
                                              const unsigned short* __restrict__ S16p,
                                              const unsigned short* __restrict__ T16p,
                                              const int* __restrict__ nidx,
                                              const float* __restrict__ sc1,
                                              const float* __restrict__ sh1,
                                              float* __restrict__ summed,
                                              float* __restrict__ psum,
                                              float* __restrict__ psq) {
    int tid = threadIdx.x;
    int w = tid >> 6, l = tid & 63;
    int c_loc = l & 15, kg = l >> 4;
    int blk = blockIdx.x;
    int s0 = blk * SPB;

    const bf16x8* wf = (const bf16x8*)(Wfrag + (size_t)w * 2048);
    bf16x8 bF0 = wf[0 * 64 + l];
    bf16x8 bF1 = wf[1 * 64 + l];
    bf16x8 bC0 = wf[2 * 64 + l];
    bf16x8 bC1 = wf[3 * 64 + l];

    int chF = w * 16 + c_loc;
    int m_off = (kg < 3) ? kg * 4 : 8;

    const unsigned short* abase = Apad + (size_t)s0 * ASTRIDE + kg * 96 + c_loc * 8;
    const unsigned int* sbase = (const unsigned int*)S16p + (size_t)s0 * 64 + chF;
    const unsigned int* Tb = (const unsigned int*)T16p + chF;

    float scF, shF, scC, shC;
    if (MODE == 1) {
        scF = sc1[chF]; shF = sh1[chF];
        scC = sc1[chF + 64]; shC = sh1[chF + 64];
    }

    float sA0 = 0.f, sB0 = 0.f, sA1 = 0.f, sB1 = 0.f;

    // rotating pipeline state (all indices compile-time after full unroll)
    bf16x8 A0[2], A1[2];
    unsigned int SD[2];
    int4 JR[2];
    unsigned int TD[2][4];

    // jr load with tail clamp (valid any sample index)
    #define LDJR(s) (*(const int4*)(nidx + min(s0 + (s), NAT - 1) * 12 + m_off))

    // prologue: sample 0 fully prefetched, sample 1's jr ready
    JR[0] = LDJR(0);
    JR[1] = LDJR(1);
    A0[0] = *(const bf16x8*)abase;
    A1[0] = *(const bf16x8*)(abase + 384);
    SD[0] = *sbase;
    TD[0][0] = Tb[(unsigned int)JR[0].x << 6];
    TD[0][1] = Tb[(unsigned int)JR[0].y << 6];
    TD[0][2] = Tb[(unsigned int)JR[0].z << 6];
    TD[0][3] = Tb[(unsigned int)JR[0].w << 6];

    #pragma unroll
    for (int si = 0; si < SPB; ++si) {
        const int p = si & 1, q = p ^ 1;
        // ---- prefetch sample si+1 (TD uses JR[q] = jr(si+1), loaded 2 iters ago)
        TD[q][0] = Tb[(unsigned int)JR[q].x << 6];
        TD[q][1] = Tb[(unsigned int)JR[q].y << 6];
        TD[q][2] = Tb[(unsigned int)JR[q].z << 6];
        TD[q][3] = Tb[(unsigned int)JR[q].w << 6];
        A0[q] = *(const bf16x8*)(abase + (si + 1) * ASTRIDE);
        A1[q] = *(const bf16x8*)(abase + (si + 1) * ASTRIDE + 384);
        SD[q] = sbase[(si + 1) * 64];
        JR[p] = LDJR(si + 2);

        // ---- compute sample si (loads issued last iteration)
        float Sf = lo_bf(SD[p]), Sc = hi_bf(SD[p]);
        f32x4 aF = { Sf + lo_bf(TD[p][0]), Sf + lo_bf(TD[p][1]),
                     Sf + lo_bf(TD[p][2]), Sf + lo_bf(TD[p][3]) };
        f32x4 aC = { Sc + hi_bf(TD[p][0]), Sc + hi_bf(TD[p][1]),
                     Sc + hi_bf(TD[p][2]), Sc + hi_bf(TD[p][3]) };
        aF = __builtin_amdgcn_mfma_f32_16x16x32_bf16(A0[p], bF0, aF, 0, 0, 0);
        aF = __builtin_amdgcn_mfma_f32_16x16x32_bf16(A1[p], bF1, aF, 0, 0, 0);
        aC = __builtin_amdgcn_mfma_f32_16x16x32_bf16(A0[p], bC0, aC, 0, 0, 0);
        aC = __builtin_amdgcn_mfma_f32_16x16x32_bf16(A1[p], bC1, aC, 0, 0, 0);

        if (MODE == 0) {
            if (kg < 3) {
                #pragma unroll
                for (int r = 0; r < 4; ++r) {
                    sA0 += aF[r]; sB0 += aF[r] * aF[r];
                    sA1 += aC[r]; sB1 += aC[r] * aC[r];
                }
            }
        } else {
            float vs = 0.f;
            if (kg < 3) {
                #pragma unroll
                for (int r = 0; r < 4; ++r) {
                    float gF = fmaf(aF[r], scF, shF);
                    float gC = fmaf(aC[r], scC, shC);
                    vs += fsig(gF) * fsp(gC);
                }
            }
            vs += __shfl_xor(vs, 16);
            vs += __shfl_xor(vs, 32);
            if (l < 16) summed[(size_t)(s0 + si) * FEA + chF] = vs;
            sA0 += vs; sB0 += vs * vs;
        }
    }
    #undef LDJR

    if (MODE == 0) {
        sA0 += __shfl_xor(sA0, 16); sA0 += __shfl_xor(sA0, 32);
        sB0 += __shfl_xor(sB0, 16); sB0 += __shfl_xor(sB0, 32);
        sA1 += __shfl_xor(sA1, 16); sA1 += __shfl_xor(sA1, 32);
        sB1 += __shfl_xor(sB1, 16); sB1 += __shfl_xor(sB1, 32);
        if (l < 16) {
            psum[(size_t)chF * CB + blk] = sA0;
            psq [(size_t)chF * CB + blk] = sB0;
            psum[(size_t)(chF + 64) * CB + blk] = sA1;
            psq [(size_t)(chF + 64) * CB + blk] = sB1;
        }
    } else {
        if (l < 16) {
            psum[(size_t)chF * CB + blk] = sA0;
            psq [(size_t)chF * CB + blk] = sB0;
        }
    }
}

// ---------------- BN finalize
__global__ __launch_bounds__(256) void k_bnfin(const float* __restrict__ psum,
                                               const float* __restrict__ psq,
                                               const float* __restrict__ g,
                                               const float* __restrict__ b,
                                               float cnt_inv,
                                               float* __restrict__ scale,
                                               float* __restrict__ shift) {
    int c = blockIdx.x;
    int tid = threadIdx.x;
    __shared__ float r1[256], r2[256];
    float s = 0.f, q = 0.f;
    for (int t = tid; t < CB; t += 256) {
        s += psum[(size_t)c * CB + t];
        q += psq[(size_t)c * CB + t];
    }
    r1[tid] = s; r2[tid] = q;
    __syncthreads();
    for (int st = 128; st > 0; st >>= 1) {
        if (tid < st) { r1[tid] += r1[tid + st]; r2[tid] += r2[tid + st]; }
        __syncthreads();
    }
    if (tid == 0) {
        float mean = r1[0] * cnt_inv;
        float var = r2[0] * cnt_inv - mean * mean;
        float sc = g[c] * rsqrtf(var + EPSV);
        scale[c] = sc;
        shift[c] = b[c] - mean * sc;
    }
}

// ---------------- residual update (float4, refreshes bf16 copy)
__global__ __launch_bounds__(256) void k_update(float* __restrict__ af,
                                                unsigned short* __restrict__ af16,
                                                const float* __restrict__ summed,
                                                const float* __restrict__ sc2,
                                                const float* __restrict__ sh2) {
    int t = blockIdx.x * 256 + threadIdx.x;
    if (t >= NAT * 16) return;
    float4 v = ((const float4*)af)[t];
    float4 s = ((const float4*)summed)[t];
    int c0 = (t & 15) * 4;
    v.x = fsp(v.x + s.x * sc2[c0 + 0] + sh2[c0 + 0]);
    v.y = fsp(v.y + s.y * sc2[c0 + 1] + sh2[c0 + 1]);
    v.z = fsp(v.z + s.z * sc2[c0 + 2] + sh2[c0 + 2]);
    v.w = fsp(v.w + s.w * sc2[c0 + 3] + sh2[c0 + 3]);
    ((float4*)af)[t] = v;
    ushort4 o = {f2bf(v.x), f2bf(v.y), f2bf(v.z), f2bf(v.w)};
    *(ushort4*)(af16 + (size_t)t * 4) = o;
}

// ---------------- fc on selected rows + mask
__global__ __launch_bounds__(256) void k_fc(const float* __restrict__ af,
                                            const int* __restrict__ sel,
                                            const float* __restrict__ mask,
                                            const float* __restrict__ W,
                                            const float* __restrict__ bias,
                                            float* __restrict__ out) {
    __shared__ float A[16][64];
    int tid = threadIdx.x;
    int r0 = blockIdx.x * 16;
    for (int t = tid; t < 16 * 64; t += 256) {
        int r = t >> 6, k = t & 63;
        int n = sel[r0 + r];
        A[r][k] = af[(size_t)n * FEA + k];
    }
    __syncthreads();
    float acc[16][3];
    #pragma unroll
    for (int r = 0; r < 16; ++r) { acc[r][0] = 0.f; acc[r][1] = 0.f; acc[r][2] = 0.f; }
    for (int k = 0; k < 64; ++k) {
        float w0 = W[(size_t)k * HIDD + tid];
        float w1 = W[(size_t)k * HIDD + 256 + tid];
        float w2 = W[(size_t)k * HIDD + 512 + tid];
        #pragma unroll
        for (int r = 0; r < 16; ++r) {
            float a = A[r][k];
            acc[r][0] = fmaf(a, w0, acc[r][0]);
            acc[r][1] = fmaf(a, w1, acc[r][1]);
            acc[r][2] = fmaf(a, w2, acc[r][2]);
        }
    }
    float b0 = bias[tid], b1 = bias[256 + tid], b2 = bias[512 + tid];
    #pragma unroll
    for (int r = 0; r < 16; ++r) {
        float mv = mask[r0 + r];
        size_t base = (size_t)(r0 + r) * HIDD;
        out[base + tid] = (acc[r][0] + b0) * mv;
        out[base + 256 + tid] = (acc[r][1] + b1) * mv;
        out[base + 512 + tid] = (acc[r][2] + b2) * mv;
    }
}

__global__ __launch_bounds__(256) void k_mask(const float* __restrict__ mask,
                                              float* __restrict__ out) {
    int idx = blockIdx.x * 256 + threadIdx.x;
    if (idx < BB * LL) out[(size_t)BB * LL * HIDD + idx] = mask[idx];
}

// ---------------------------------------------------------------- launch
extern "C" void kernel_launch(void* const* d_in, const int* in_sizes, int n_in,
                              void* d_out, int out_size, void* d_ws, size_t ws_size,
                              hipStream_t stream) {
    const int* atom_num  = (const int*)d_in[0];
    const int* nbr_idx   = (const int*)d_in[1];
    const float* nbr_fea = (const float*)d_in[2];
    const int* sel_idx   = (const int*)d_in[3];
    const float* mask    = (const float*)d_in[4];
    const float* emb     = (const float*)d_in[5];
    const float* conv_W  = (const float*)d_in[6];
    const float* conv_b  = (const float*)d_in[7];
    const float* bn1_g   = (const float*)d_in[8];
    const float* bn1_b   = (const float*)d_in[9];
    const float* bn2_g   = (const float*)d_in[10];
    const float* bn2_b   = (const float*)d_in[11];
    const float* fc_W    = (const float*)d_in[12];
    const float* fc_b    = (const float*)d_in[13];
    float* out = (float*)d_out;

    char* p = (char*)d_ws;
    float* af = (float*)p;                      p += (size_t)NAT * FEA * 4;
    unsigned short* af16 = (unsigned short*)p;  p += (size_t)NAT * FEA * 2;
    unsigned short* S16p = (unsigned short*)p;  p += (size_t)NAT * C2 * 2;
    unsigned short* T16p = (unsigned short*)p;  p += (size_t)NAT * C2 * 2;
    float* summed = (float*)p;                  p += (size_t)NAT * FEA * 4;
    float* sc1 = (float*)p;                     p += 512;
    float* sh1 = (float*)p;                     p += 512;
    float* sc2 = (float*)p;                     p += 512;
    float* sh2 = (float*)p;                     p += 512;
    unsigned short* Wfrag = (unsigned short*)p; p += 16384;
    unsigned short* Wf2 = (unsigned short*)p;   p += 32768;
    unsigned short* Apad = (unsigned short*)p;  p += (size_t)APAD_SAMP * ASTRIDE * 2;
    float* psum = (float*)p;                    p += (size_t)C2 * CB * 4;
    float* psq = (float*)p;                     p += (size_t)C2 * CB * 4;

    k_embed<<<(NAT * FEA) / 256, 256, 0, stream>>>(atom_num, emb, af, af16);
    k_prepad<<<(APAD_SAMP * 72 + 255) / 256, 256, 0, stream>>>(nbr_fea, Apad);

    for (int i = 0; i < NCONV; ++i) {
        const float* Wb = conv_W + (size_t)i * 169 * C2;
        k_wfrag<<<32, 256, 0, stream>>>(Wb, Wfrag);
        k_wfrag2<<<64, 256, 0, stream>>>(Wb, Wf2);
        k_st2<<<STG, 256, 0, stream>>>(af16, Wf2, conv_b + i * C2, S16p, T16p);
        k_conv<0><<<CB, 256, 0, stream>>>(Apad, Wfrag, S16p, T16p, nbr_idx,
                                          sc1, sh1, summed, psum, psq);
        k_bnfin<<<C2, 256, 0, stream>>>(psum, psq, bn1_g + i * C2, bn1_b + i * C2,
                                        1.f / (float)(NAT * (long)MNB), sc1, sh1);
        k_conv<1><<<CB, 256, 0, stream>>>(Apad, Wfrag, S16p, T16p, nbr_idx,
                                          sc1, sh1, summed, psum, psq);
        k_bnfin<<<FEA, 256, 0, stream>>>(psum, psq, bn2_g + i * FEA, bn2_b + i * FEA,
                                         1.f / (float)NAT, sc2, sh2);
        k_update<<<(NAT * 16) / 256, 256, 0, stream>>>(af, af16, summed, sc2, sh2);
    }

    k_fc<<<BB * LL / 16, 256, 0, stream>>>(af, sel_idx, mask, fc_W, fc_b, out);
    k_mask<<<(BB * LL + 255) / 256, 256, 0, stream>>>(mask, out);
}